// Round 8
// baseline (288.475 us; speedup 1.0000x reference)
//
#include <hip/hip_runtime.h>
#include <hip/hip_bf16.h>

// ---------------------------------------------------------------------------
// HybridFusionNetworkWithUncertainty — MI355X (gfx950), round 8
// Mega-fused stage A: intra GEMM (64x512, B-frags DIRECT global->reg, no LDS
// for B) + ReLU + LayerNorm (h in LDS) + qv GEMM (A-frags from h-LDS, B
// direct-to-reg, barrier-free) -> qvout. LDS = A dbuf 8K + h 64K = 72KB,
// 2 blocks/CU. w1 keeps r7 core_db. attn/fc unchanged.
// ws layout (clobber-free): [0,3.4M) bf16 weights (prep) ; zbuf [8M,40M) ;
// obuf [40M,56M) ; qvout [64M,128M).
// ---------------------------------------------------------------------------

typedef __bf16 bf16;
typedef __bf16 bf16x4_t __attribute__((ext_vector_type(4)));
typedef __bf16 bf16x8_t __attribute__((ext_vector_type(8)));
typedef float  f32x4_t  __attribute__((ext_vector_type(4)));

__device__ __forceinline__ bf16x8_t cvt8(f32x4_t a, f32x4_t b) {
  bf16x8_t r;
  r[0] = (bf16)a[0]; r[1] = (bf16)a[1]; r[2] = (bf16)a[2]; r[3] = (bf16)a[3];
  r[4] = (bf16)b[0]; r[5] = (bf16)b[1]; r[6] = (bf16)b[2]; r[7] = (bf16)b[3];
  return r;
}

__device__ __forceinline__ void gl_lds16(const void* g, void* l) {
  __builtin_amdgcn_global_load_lds(
      (const __attribute__((address_space(1))) void*)g,
      (__attribute__((address_space(3))) void*)l, 16, 0, 0);
}

// 32-wide LDS tile (A): row = 4 chunks of 16B; chunk c at c ^ ((r>>1)&3).
__device__ __forceinline__ bf16x8_t frag_read(const bf16* Ts, int row, int c0) {
  const int byte = row * 64 + ((c0 ^ ((row >> 1) & 3)) << 4);
  return *(const bf16x8_t*)((const char*)Ts + byte);
}

#define WAIT_VM6()  asm volatile("s_waitcnt vmcnt(6)" ::: "memory")
#define WAIT_VM0()  asm volatile("s_waitcnt vmcnt(0)" ::: "memory")
#define WAIT_LGKM() asm volatile("s_waitcnt lgkmcnt(0)" ::: "memory")
#define SBAR()      __builtin_amdgcn_s_barrier()
#define SCHED0()    __builtin_amdgcn_sched_barrier(0)

// load 8 B-fragments direct global->reg: base pre-offset by (wn*128+fr)*ld + g*8
__device__ __forceinline__ void loadB8(const bf16* __restrict__ base, int ld,
                                       int k0, bf16x8_t br[8]) {
#pragma unroll
  for (int ni = 0; ni < 8; ++ni)
    br[ni] = *(const bf16x8_t*)(base + (size_t)ni * 16 * ld + k0);
}

// MFMA: A from 64x32 LDS tile, B from regs; 4x8 frags (wave = 64 rows x 128 cols)
__device__ __forceinline__ void mfma_regB(const bf16* As, const bf16x8_t br[8],
                                          f32x4_t acc[4][8]) {
  const int lane = threadIdx.x & 63;
  const int fr = lane & 15, c0 = lane >> 4;
  bf16x8_t ar[4];
#pragma unroll
  for (int mi = 0; mi < 4; ++mi) ar[mi] = frag_read(As, mi * 16 + fr, c0);
#pragma unroll
  for (int mi = 0; mi < 4; ++mi)
#pragma unroll
    for (int ni = 0; ni < 8; ++ni)
      acc[mi][ni] = __builtin_amdgcn_mfma_f32_16x16x32_bf16(ar[mi], br[ni], acc[mi][ni], 0, 0, 0);
}

// MFMA: A from h-LDS ([64][512] bf16, chunk swizzle c^(r&7)), B from regs.
__device__ __forceinline__ void mfma_hA(const bf16* h, int kc, const bf16x8_t br[8],
                                        f32x4_t acc[4][8]) {
  const int lane = threadIdx.x & 63;
  const int fr = lane & 15, g = lane >> 4;
  bf16x8_t ar[4];
#pragma unroll
  for (int mi = 0; mi < 4; ++mi) {
    const int row = mi * 16 + fr;
    const int byte = row * 1024 + (((kc + g) ^ (row & 7)) << 4);
    ar[mi] = *(const bf16x8_t*)((const char*)h + byte);
  }
#pragma unroll
  for (int mi = 0; mi < 4; ++mi)
#pragma unroll
    for (int ni = 0; ni < 8; ++ni)
      acc[mi][ni] = __builtin_amdgcn_mfma_f32_16x16x32_bf16(ar[mi], br[ni], acc[mi][ni], 0, 0, 0);
}

// ---- prep: weights f32 -> bf16 (wb0-3 + wqv = Wq||Wv) ----
__device__ __forceinline__ void cp8(bf16* d, const float* s) {
  f32x4_t x0 = *(const f32x4_t*)s;
  f32x4_t x1 = *(const f32x4_t*)(s + 4);
  *(bf16x8_t*)d = cvt8(x0, x1);
}

__global__ __launch_bounds__(256) void prep_kernel(
    const float* __restrict__ w0, const float* __restrict__ w1s,
    const float* __restrict__ w2, const float* __restrict__ w3,
    const float* __restrict__ wq, const float* __restrict__ wv,
    bf16* __restrict__ o0, bf16* __restrict__ o1, bf16* __restrict__ o2,
    bf16* __restrict__ o3, bf16* __restrict__ oqv) {
  const int t = blockIdx.x * 256 + threadIdx.x;    // 864 blocks = 221184 threads
  if (t < 65536)       { size_t i = (size_t)t * 8;            cp8(o0 + i, w0 + i); }
  else if (t < 114688) { size_t i = (size_t)(t - 65536) * 8;  cp8(o1 + i, w1s + i); }
  else if (t < 147456) { size_t i = (size_t)(t - 114688) * 8; cp8(o2 + i, w2 + i); }
  else if (t < 188416) { size_t i = (size_t)(t - 147456) * 8; cp8(o3 + i, w3 + i); }
  else                 { int u = t - 188416; size_t i = (size_t)u * 8;
                         cp8(oqv + i, (u < 16384) ? wq + i : wv + (i - 131072)); }
}

// ---- mega: intra GEMM + relu + LN + qv GEMM -> qvout ----
__global__ __launch_bounds__(256, 2) void mega_kernel(
    const float* __restrict__ f0, const float* __restrict__ f1,
    const float* __restrict__ f2, const float* __restrict__ f3,
    const bf16* __restrict__ wb0, const bf16* __restrict__ wb1,
    const bf16* __restrict__ wb2, const bf16* __restrict__ wb3,
    const float* __restrict__ bb0, const float* __restrict__ bb1,
    const float* __restrict__ bb2, const float* __restrict__ bb3,
    const float* __restrict__ lng, const float* __restrict__ lnb,
    const bf16* __restrict__ wqv, const float* __restrict__ bq,
    const float* __restrict__ bv, bf16* __restrict__ qvout) {
  __shared__ bf16 A0[64 * 32];                     // 4K
  __shared__ bf16 A1[64 * 32];                     // 4K
  __shared__ bf16 h[64 * 512];                     // 64K  -> total 72K, 2 blk/CU

  const int bid = blockIdx.x;                      // 1024 blocks
  const int lid = (bid & 7) * 128 + (bid >> 3);    // XCD-chunked bijection
  const int z = lid & 3;                           // model
  const int y = lid >> 2;                          // M-block (0..255), 64 rows
  const float* fp; const bf16* wp; const float* bp; int K;
  switch (z) {
    case 0:  fp = f0; wp = wb0; bp = bb0; K = 1024; break;
    case 1:  fp = f1; wp = wb1; bp = bb1; K = 768;  break;
    case 2:  fp = f2; wp = wb2; bp = bb2; K = 512;  break;
    default: fp = f3; wp = wb3; bp = bb3; K = 640;  break;
  }
  const int tid  = threadIdx.x;
  const int lane = tid & 63;
  const int wn   = tid >> 6;                       // wave -> cols wn*128..+128
  const int fr   = lane & 15, g = lane >> 4;
  const int srow = tid >> 2, sq = tid & 3;         // A staging: 4 thr/row, 8 f32
  const float* Af = fp + (size_t)(y * 64 + srow) * K + sq * 8;
  const int abyte = srow * 64 + ((sq ^ ((srow >> 1) & 3)) << 4);
  const bf16* Bbase = wp + (size_t)(wn * 128 + fr) * K + g * 8;

  f32x4_t acc[4][8];
#pragma unroll
  for (int i = 0; i < 4; ++i)
#pragma unroll
    for (int j = 0; j < 8; ++j) acc[i][j] = (f32x4_t){0.f, 0.f, 0.f, 0.f};

  // ---- intra K-loop: A via LDS dbuf (f32->bf16), B direct-to-reg dbuf ----
  f32x4_t ra0, ra1, rb0, rb1;
  bf16x8_t bc[8], bn[8];
  ra0 = *(const f32x4_t*)(Af + 0);  ra1 = *(const f32x4_t*)(Af + 4);
  loadB8(Bbase, K, 0, bc);

  for (int k0 = 0; k0 < K; k0 += 64) {
    // half 1: compute tile k0 (A0, bc); prefetch k0+32
    loadB8(Bbase, K, k0 + 32, bn);
    rb0 = *(const f32x4_t*)(Af + k0 + 32);  rb1 = *(const f32x4_t*)(Af + k0 + 36);
    *(bf16x8_t*)((char*)A0 + abyte) = cvt8(ra0, ra1);
    WAIT_LGKM();
    SBAR(); SCHED0();
    mfma_regB(A0, bc, acc);
    SCHED0(); SBAR();
    // half 2: compute tile k0+32 (A1, bn); prefetch k0+64
    if (k0 + 64 < K) {
      loadB8(Bbase, K, k0 + 64, bc);
      ra0 = *(const f32x4_t*)(Af + k0 + 64);  ra1 = *(const f32x4_t*)(Af + k0 + 68);
    }
    *(bf16x8_t*)((char*)A1 + abyte) = cvt8(rb0, rb1);
    WAIT_LGKM();
    SBAR(); SCHED0();
    mfma_regB(A1, bn, acc);
    SCHED0(); SBAR();
  }

  // ---- epilogue: bias + relu -> h (swizzled [64][512]) ----
  const int g4 = 4 * g;
  {
    float bv8[8];
#pragma unroll
    for (int ni = 0; ni < 8; ++ni) bv8[ni] = bp[wn * 128 + ni * 16 + fr];
#pragma unroll
    for (int mi = 0; mi < 4; ++mi)
#pragma unroll
      for (int j = 0; j < 4; ++j) {
        const int row = mi * 16 + g4 + j;
#pragma unroll
        for (int ni = 0; ni < 8; ++ni) {
          const int col = wn * 128 + ni * 16 + fr;
          const int hb = row * 1024 + (((col >> 3) ^ (row & 7)) << 4) + (col & 7) * 2;
          float v = fmaxf(acc[mi][ni][j] + bv8[ni], 0.f);
          *(bf16*)((char*)h + hb) = (bf16)v;
        }
      }
  }
  __syncthreads();

  // ---- LayerNorm in h: wave wn -> rows wn*16..+15; lane -> chunk=lane ----
  {
    f32x4_t gg0 = *(const f32x4_t*)(lng + lane * 8);
    f32x4_t gg1 = *(const f32x4_t*)(lng + lane * 8 + 4);
    f32x4_t be0 = *(const f32x4_t*)(lnb + lane * 8);
    f32x4_t be1 = *(const f32x4_t*)(lnb + lane * 8 + 4);
#pragma unroll
    for (int r16 = 0; r16 < 16; ++r16) {
      const int row = wn * 16 + r16;
      const int hb = row * 1024 + ((lane ^ (row & 7)) << 4);
      const bf16x8_t xv = *(const bf16x8_t*)((const char*)h + hb);
      float xf[8]; float s = 0.f, s2 = 0.f;
#pragma unroll
      for (int j = 0; j < 8; ++j) { xf[j] = (float)xv[j]; s += xf[j]; s2 += xf[j] * xf[j]; }
#pragma unroll
      for (int off = 1; off < 64; off <<= 1) { s += __shfl_xor(s, off); s2 += __shfl_xor(s2, off); }
      const float mu  = s * (1.f / 512.f);
      const float var = s2 * (1.f / 512.f) - mu * mu;
      const float inv = rsqrtf(var + 1e-5f);
      bf16x8_t o;
#pragma unroll
      for (int j = 0; j < 4; ++j) o[j]     = (bf16)((xf[j] - mu) * inv * gg0[j] + be0[j]);
#pragma unroll
      for (int j = 0; j < 4; ++j) o[4 + j] = (bf16)((xf[4 + j] - mu) * inv * gg1[j] + be1[j]);
      *(bf16x8_t*)((char*)h + hb) = o;
    }
  }
  __syncthreads();

  // ---- qv GEMM: A from h-LDS, B (wqv) direct-to-reg; barrier-free ----
#pragma unroll
  for (int i = 0; i < 4; ++i)
#pragma unroll
    for (int j = 0; j < 8; ++j) acc[i][j] = (f32x4_t){0.f, 0.f, 0.f, 0.f};
  const bf16* Qbase = wqv + (size_t)(wn * 128 + fr) * 512 + g * 8;
  bf16x8_t qc[8], qn[8];
  loadB8(Qbase, 512, 0, qc);
  for (int k0 = 0; k0 < 512; k0 += 64) {
    loadB8(Qbase, 512, k0 + 32, qn);
    mfma_hA(h, k0 >> 3, qc, acc);
    if (k0 + 64 < 512) loadB8(Qbase, 512, k0 + 64, qc);
    mfma_hA(h, (k0 + 32) >> 3, qn, acc);
  }

  // ---- qv epilogue -> qvout[(b*4+z)*512 + col] ----
  {
    float bv8[8];
#pragma unroll
    for (int ni = 0; ni < 8; ++ni) {
      const int col = wn * 128 + ni * 16 + fr;
      bv8[ni] = (col < 256) ? bq[col] : bv[col - 256];
    }
#pragma unroll
    for (int mi = 0; mi < 4; ++mi)
#pragma unroll
      for (int j = 0; j < 4; ++j) {
        const int row = mi * 16 + g4 + j;
        bf16* outp = qvout + ((size_t)(y * 64 + row) * 4 + z) * 512;
#pragma unroll
        for (int ni = 0; ni < 8; ++ni) {
          const int col = wn * 128 + ni * 16 + fr;
          outp[col] = (bf16)(acc[mi][ni][j] + bv8[ni]);
        }
      }
  }
}

// ---- w1 helpers (r7 core_db, unchanged) ----
__device__ __forceinline__ void stage_b16(const bf16* __restrict__ src, int ld,
                                          int k0, bf16* lds) {
  const int l = threadIdx.x & 63;
  const int w = threadIdx.x >> 6;
#pragma unroll
  for (int j = 0; j < 2; ++j) {
    const int rb = w * 32 + j * 16;
    const int r  = rb + (l >> 2);
    const int sc = (l & 3) ^ ((r >> 1) & 3);
    gl_lds16(src + (size_t)r * ld + k0 + sc * 8, (char*)lds + rb * 64);
  }
}

__device__ __forceinline__ void commit2(const f32x4_t v[4], bf16* lds,
                                        int srow, int shalf) {
  const int sw = (srow >> 1) & 3;
  *(bf16x8_t*)((char*)lds + srow * 64 + (((shalf * 2)     ^ sw) << 4)) = cvt8(v[0], v[1]);
  *(bf16x8_t*)((char*)lds + srow * 64 + (((shalf * 2 + 1) ^ sw) << 4)) = cvt8(v[2], v[3]);
}

__device__ __forceinline__ void mfma_step(const bf16* As, const bf16* Bs,
                                          f32x4_t acc[4][4]) {
  const int lane = threadIdx.x & 63;
  const int wid  = threadIdx.x >> 6;
  const int wm = wid >> 1, wn = wid & 1;
  const int fr = lane & 15, c0 = lane >> 4;
  bf16x8_t ar[4], br[4];
#pragma unroll
  for (int mi = 0; mi < 4; ++mi) ar[mi] = frag_read(As, wm * 64 + mi * 16 + fr, c0);
#pragma unroll
  for (int ni = 0; ni < 4; ++ni) br[ni] = frag_read(Bs, wn * 64 + ni * 16 + fr, c0);
#pragma unroll
  for (int mi = 0; mi < 4; ++mi)
#pragma unroll
    for (int ni = 0; ni < 4; ++ni)
      acc[mi][ni] = __builtin_amdgcn_mfma_f32_16x16x32_bf16(ar[mi], br[ni], acc[mi][ni], 0, 0, 0);
}

__device__ __forceinline__ void core_db0(
    const float* __restrict__ regsrc, int rld,
    const bf16* __restrict__ dmasrc, int dld, int K,
    bf16* R0, bf16* R1, bf16* D0, bf16* D1, f32x4_t acc[4][4])
{
  const int tid  = threadIdx.x;
  const int srow = tid >> 1, shalf = tid & 1;
  const float* Rf = regsrc + (size_t)srow * rld + shalf * 16;
  f32x4_t ra[4], rb[4];
#pragma unroll
  for (int i = 0; i < 4; ++i) ra[i] = *(const f32x4_t*)(Rf + i * 4);
  stage_b16(dmasrc, dld, 0, D0);
  for (int k0 = 0; k0 < K; k0 += 64) {
    stage_b16(dmasrc, dld, k0 + 32, D1);
#pragma unroll
    for (int i = 0; i < 4; ++i) rb[i] = *(const f32x4_t*)(Rf + k0 + 32 + i * 4);
    WAIT_VM6();
    commit2(ra, R0, srow, shalf);
    WAIT_LGKM();
    SBAR(); SCHED0();
    mfma_step(D0, R0, acc);
    SCHED0(); SBAR();
    if (k0 + 64 < K) {
      stage_b16(dmasrc, dld, k0 + 64, D0);
#pragma unroll
      for (int i = 0; i < 4; ++i) ra[i] = *(const f32x4_t*)(Rf + k0 + 64 + i * 4);
      WAIT_VM6();
    } else {
      WAIT_VM0();
    }
    commit2(rb, R1, srow, shalf);
    WAIT_LGKM();
    SBAR(); SCHED0();
    mfma_step(D1, R1, acc);
    SCHED0(); SBAR();
  }
}

// ---- stage E: W1 GEMM (K=1024, ldw=1028) + pred_scores rank-4 fixup ----
__global__ __launch_bounds__(256) void w1_kernel(
    const bf16* __restrict__ zb, const float* __restrict__ W1,
    const float* __restrict__ b1, const float* __restrict__ ps,
    float* __restrict__ obuf) {
  __shared__ bf16 A0[128 * 32], A1[128 * 32], B0[128 * 32], B1[128 * 32];
  const int bid = blockIdx.x;                     // 256 blocks
  const int lid = (bid & 7) * 32 + (bid >> 3);
  const int x = lid & 1, y = lid >> 1;            // y: 0..127
  f32x4_t acc[4][4];
#pragma unroll
  for (int i = 0; i < 4; ++i)
#pragma unroll
    for (int j = 0; j < 4; ++j) acc[i][j] = (f32x4_t){0.f, 0.f, 0.f, 0.f};
  core_db0(W1 + (size_t)(x * 128) * 1028, 1028,
           zb + (size_t)(y * 128) * 1024, 1024, 1024, B0, B1, A0, A1, acc);

  const int lane = threadIdx.x & 63;
  const int wid  = threadIdx.x >> 6;
  const int wm = wid >> 1, wn = wid & 1;
  const int fr = lane & 15;
  const int rb = wm * 64 + 4 * (lane >> 4);
  const int cb = x * 128 + wn * 64 + fr;
  float bv[4], wt[4][4];
#pragma unroll
  for (int ni = 0; ni < 4; ++ni) {
    bv[ni] = b1[cb + ni * 16];
#pragma unroll
    for (int m = 0; m < 4; ++m) wt[ni][m] = W1[(size_t)(cb + ni * 16) * 1028 + 1024 + m];
  }
#pragma unroll
  for (int mi = 0; mi < 4; ++mi)
#pragma unroll
    for (int j = 0; j < 4; ++j) {
      const int r = y * 128 + rb + mi * 16 + j;
      f32x4_t psv = *(const f32x4_t*)(ps + (size_t)r * 4);
#pragma unroll
      for (int ni = 0; ni < 4; ++ni) {
        float val = acc[mi][ni][j] + bv[ni]
                  + psv[0] * wt[ni][0] + psv[1] * wt[ni][1]
                  + psv[2] * wt[ni][2] + psv[3] * wt[ni][3];
        obuf[(size_t)r * 256 + cb + ni * 16] = val;
      }
    }
}

// ---- attention: 4x4 scores (k=q per source bug), softmax(-UW*(vi+vj)), z=s@v ----
__global__ __launch_bounds__(256)
void attn_kernel(const bf16* __restrict__ qv, const float* __restrict__ pvars,
                 bf16* __restrict__ z) {
  const int b    = blockIdx.x * 4 + (threadIdx.x >> 6);
  const int lane = threadIdx.x & 63;
  float qf[4][4], vf[4][4];
#pragma unroll
  for (int i = 0; i < 4; ++i) {
    const bf16* row = qv + ((size_t)b * 4 + i) * 512;
    bf16x4_t qq = *(const bf16x4_t*)(row + lane * 4);
    bf16x4_t vv = *(const bf16x4_t*)(row + 256 + lane * 4);
#pragma unroll
    for (int c = 0; c < 4; ++c) { qf[i][c] = (float)qq[c]; vf[i][c] = (float)vv[c]; }
  }
  float s[4][4];
#pragma unroll
  for (int i = 0; i < 4; ++i)
#pragma unroll
    for (int j = 0; j < 4; ++j)
      s[i][j] = qf[i][0] * qf[j][0] + qf[i][1] * qf[j][1] + qf[i][2] * qf[j][2] + qf[i][3] * qf[j][3];
#pragma unroll
  for (int off = 1; off < 64; off <<= 1)
#pragma unroll
    for (int i = 0; i < 4; ++i)
#pragma unroll
      for (int j = 0; j < 4; ++j) s[i][j] += __shfl_xor(s[i][j], off);

  float var4[4];
#pragma unroll
  for (int m = 0; m < 4; ++m) var4[m] = pvars[(size_t)b * 4 + m];
  float w[4][4];
#pragma unroll
  for (int i = 0; i < 4; ++i) {
    float t[4]; float mx = -1e30f;
#pragma unroll
    for (int j = 0; j < 4; ++j) { t[j] = s[i][j] - 0.1f * (var4[i] + var4[j]); mx = fmaxf(mx, t[j]); }
    float sum = 0.f;
#pragma unroll
    for (int j = 0; j < 4; ++j) { t[j] = expf(t[j] - mx); sum += t[j]; }
    const float is = 1.f / sum;
#pragma unroll
    for (int j = 0; j < 4; ++j) w[i][j] = t[j] * is;
  }
#pragma unroll
  for (int i = 0; i < 4; ++i) {
    bf16x4_t zo;
#pragma unroll
    for (int c = 0; c < 4; ++c) {
      float zf = w[i][0] * vf[0][c] + w[i][1] * vf[1][c] + w[i][2] * vf[2][c] + w[i][3] * vf[3][c];
      zo[c] = (bf16)zf;
    }
    *(bf16x4_t*)(z + ((size_t)b * 4 + i) * 256 + lane * 4) = zo;
  }
}

// ---- final fc (256 -> 1) + sigmoid ----
__global__ __launch_bounds__(256)
void fc_kernel(const float* __restrict__ o, const float* __restrict__ wfc,
               const float* __restrict__ bfc, float* __restrict__ out) {
  const int b    = blockIdx.x * 4 + (threadIdx.x >> 6);
  const int lane = threadIdx.x & 63;
  f32x4_t ov = *(const f32x4_t*)(o + (size_t)b * 256 + lane * 4);
  f32x4_t wv = *(const f32x4_t*)(wfc + lane * 4);
  float p = ov[0] * wv[0] + ov[1] * wv[1] + ov[2] * wv[2] + ov[3] * wv[3];
#pragma unroll
  for (int off = 1; off < 64; off <<= 1) p += __shfl_xor(p, off);
  if (lane == 0) {
    const float lg = p + bfc[0];
    out[b] = 1.f / (1.f + expf(-lg));
  }
}

extern "C" void kernel_launch(void* const* d_in, const int* in_sizes, int n_in,
                              void* d_out, int out_size, void* d_ws, size_t ws_size,
                              hipStream_t stream) {
  (void)in_sizes; (void)n_in; (void)out_size; (void)ws_size;
  const float* feat[4] = {(const float*)d_in[0], (const float*)d_in[3],
                          (const float*)d_in[6], (const float*)d_in[9]};
  const float* Wi[4]   = {(const float*)d_in[1], (const float*)d_in[4],
                          (const float*)d_in[7], (const float*)d_in[10]};
  const float* bi[4]   = {(const float*)d_in[2], (const float*)d_in[5],
                          (const float*)d_in[8], (const float*)d_in[11]};
  const float* ps  = (const float*)d_in[12];
  const float* pv  = (const float*)d_in[13];
  const float* lng = (const float*)d_in[14];
  const float* lnb = (const float*)d_in[15];
  const float* Wq  = (const float*)d_in[16];
  const float* bq  = (const float*)d_in[17];
  const float* Wv  = (const float*)d_in[20];
  const float* bvp = (const float*)d_in[21];
  const float* W1  = (const float*)d_in[22];
  const float* b1  = (const float*)d_in[23];
  const float* Wfc = (const float*)d_in[24];
  const float* bfc = (const float*)d_in[25];

  char* ws = (char*)d_ws;
  const size_t MB = 1024 * 1024;
  bf16*  wb0   = (bf16*)(ws);                      // [0, 1M)
  bf16*  wb1   = (bf16*)(ws + 1048576);            // [1M, 1.75M)
  bf16*  wb2   = (bf16*)(ws + 1835008);            // [1.75M, 2.25M)
  bf16*  wb3   = (bf16*)(ws + 2359296);            // [2.25M, 2.875M)
  bf16*  wqv   = (bf16*)(ws + 3014656);            // [2.875M+, 3.375M)
  bf16*  zbuf  = (bf16*)(ws + 8 * MB);             // [8M, 40M)
  float* obuf  = (float*)(ws + 40 * MB);           // [40M, 56M)
  bf16*  qvout = (bf16*)(ws + 64 * MB);            // [64M, 128M)

  hipLaunchKernelGGL(prep_kernel, dim3(864), dim3(256), 0, stream,
                     Wi[0], Wi[1], Wi[2], Wi[3], Wq, Wv,
                     wb0, wb1, wb2, wb3, wqv);
  hipLaunchKernelGGL(mega_kernel, dim3(1024), dim3(256), 0, stream,
                     feat[0], feat[1], feat[2], feat[3],
                     wb0, wb1, wb2, wb3, bi[0], bi[1], bi[2], bi[3],
                     lng, lnb, wqv, bq, bvp, qvout);
  hipLaunchKernelGGL(attn_kernel, dim3(16384 / 4), dim3(256), 0, stream, qvout, pv, zbuf);
  hipLaunchKernelGGL(w1_kernel, dim3(256), dim3(256), 0, stream, zbuf, W1, b1, ps, obuf);
  hipLaunchKernelGGL(fc_kernel, dim3(16384 / 4), dim3(256), 0, stream, obuf, Wfc, bfc, (float*)d_out);
}

// Round 9
// 256.361 us; speedup vs baseline: 1.1253x; 1.1253x over previous
//
#include <hip/hip_runtime.h>
#include <hip/hip_bf16.h>

// ---------------------------------------------------------------------------
// HybridFusionNetworkWithUncertainty — MI355X (gfx950), round 9
// 3-deep pipelined GEMM core: ALL staging via global_load_lds (f32 operand
// staged as f32-in-LDS, converted at fragment read), 3x24KB LDS buffers,
// counted vmcnt(12/6/0) keeps 2 tiles in flight across barriers, setprio(1)
// around MFMA. Swizzle: 16B-chunk q^(r&7) (f32 rows) / c^((r>>1)&3) (bf16
// rows), applied on DMA source AND read (involution, rule #21).
// Layout (=r7, audited): H [0,64M) (intra->ln in-place); qvout [64M,128M)
// (clobbers wb* after intra); zbuf [0,32M); obuf [32M,48M).
// ---------------------------------------------------------------------------

typedef __bf16 bf16;
typedef __bf16 bf16x4_t __attribute__((ext_vector_type(4)));
typedef __bf16 bf16x8_t __attribute__((ext_vector_type(8)));
typedef float  f32x4_t  __attribute__((ext_vector_type(4)));

__device__ __forceinline__ bf16x8_t cvt8(f32x4_t a, f32x4_t b) {
  bf16x8_t r;
  r[0] = (bf16)a[0]; r[1] = (bf16)a[1]; r[2] = (bf16)a[2]; r[3] = (bf16)a[3];
  r[4] = (bf16)b[0]; r[5] = (bf16)b[1]; r[6] = (bf16)b[2]; r[7] = (bf16)b[3];
  return r;
}

__device__ __forceinline__ void gl_lds16(const void* g, void* l) {
  __builtin_amdgcn_global_load_lds(
      (const __attribute__((address_space(1))) void*)g,
      (__attribute__((address_space(3))) void*)l, 16, 0, 0);
}

#define SBAR()   __builtin_amdgcn_s_barrier()
#define SCHED0() __builtin_amdgcn_sched_barrier(0)

// ---- bf16 tile [128 rows][32 bf16] (8KB): chunk c of row r at c^((r>>1)&3) ----
__device__ __forceinline__ bf16x8_t frag_b16(const bf16* Ts, int row, int c0) {
  const int byte = row * 64 + ((c0 ^ ((row >> 1) & 3)) << 4);
  return *(const bf16x8_t*)((const char*)Ts + byte);
}
__device__ __forceinline__ void stage_b16(const bf16* __restrict__ src, int ld,
                                          int k0, bf16* lds) {
  const int l = threadIdx.x & 63;
  const int w = threadIdx.x >> 6;
#pragma unroll
  for (int j = 0; j < 2; ++j) {
    const int rb = w * 32 + j * 16;
    const int r  = rb + (l >> 2);
    const int sc = (l & 3) ^ ((r >> 1) & 3);
    gl_lds16(src + (size_t)r * ld + k0 + sc * 8, (char*)lds + rb * 64);
  }
}

// ---- f32 tile [128 rows][32 f32] (16KB): 16B chunk q of row r at q^(r&7) ----
__device__ __forceinline__ bf16x8_t frag_f32(const float* Ts, int row, int g) {
  const int p0 = (2 * g)     ^ (row & 7);
  const int p1 = (2 * g + 1) ^ (row & 7);
  f32x4_t lo = *(const f32x4_t*)((const char*)Ts + row * 128 + (p0 << 4));
  f32x4_t hi = *(const f32x4_t*)((const char*)Ts + row * 128 + (p1 << 4));
  return cvt8(lo, hi);
}
__device__ __forceinline__ void stage_f32(const float* __restrict__ src, int ld,
                                          int k0, float* lds) {
  const int l = threadIdx.x & 63;
  const int w = threadIdx.x >> 6;
#pragma unroll
  for (int j = 0; j < 4; ++j) {
    const int rb = w * 32 + j * 8;
    const int r  = rb + (l >> 3);
    const int q  = (l & 7) ^ (r & 7);
    gl_lds16(src + (size_t)r * ld + k0 + q * 4, (char*)lds + rb * 128);
  }
}

// ---- 3-deep core: 128x128xBK32, buf = [A][B] 24KB; 6 vm-ops per tile ----
// AF32=1: A f32-in-LDS (16KB) + B bf16 (8KB). AF32=0: A bf16 (8KB) + B f32 (16KB).
template<int AF32>
__device__ __forceinline__ void stage_deep(const void* A, int lda, const void* B,
                                           int ldb, int k0, char* buf) {
  if (AF32) {
    stage_f32((const float*)A, lda, k0, (float*)buf);
    stage_b16((const bf16*)B, ldb, k0, (bf16*)(buf + 16384));
  } else {
    stage_b16((const bf16*)A, lda, k0, (bf16*)buf);
    stage_f32((const float*)B, ldb, k0, (float*)(buf + 8192));
  }
}

template<int AF32>
__device__ __forceinline__ void mfma_deep(const char* buf, f32x4_t acc[4][4]) {
  const int lane = threadIdx.x & 63;
  const int wid  = threadIdx.x >> 6;
  const int wm = wid >> 1, wn = wid & 1;
  const int fr = lane & 15, g = lane >> 4;
  bf16x8_t ar[4], br[4];
  if (AF32) {
    const float* Af = (const float*)buf;
    const bf16*  Bb = (const bf16*)(buf + 16384);
#pragma unroll
    for (int mi = 0; mi < 4; ++mi) ar[mi] = frag_f32(Af, wm * 64 + mi * 16 + fr, g);
#pragma unroll
    for (int ni = 0; ni < 4; ++ni) br[ni] = frag_b16(Bb, wn * 64 + ni * 16 + fr, g);
  } else {
    const bf16*  Ab = (const bf16*)buf;
    const float* Bf = (const float*)(buf + 8192);
#pragma unroll
    for (int mi = 0; mi < 4; ++mi) ar[mi] = frag_b16(Ab, wm * 64 + mi * 16 + fr, g);
#pragma unroll
    for (int ni = 0; ni < 4; ++ni) br[ni] = frag_f32(Bf, wn * 64 + ni * 16 + fr, g);
  }
#pragma unroll
  for (int mi = 0; mi < 4; ++mi)
#pragma unroll
    for (int ni = 0; ni < 4; ++ni)
      acc[mi][ni] = __builtin_amdgcn_mfma_f32_16x16x32_bf16(ar[mi], br[ni], acc[mi][ni], 0, 0, 0);
}

template<int AF32>
__device__ __forceinline__ void core_deep3(const void* A, int lda, const void* B,
                                           int ldb, int K, char* lds,
                                           f32x4_t acc[4][4]) {
  const int nt = K >> 5;                       // >= 16 for all our shapes
  stage_deep<AF32>(A, lda, B, ldb, 0,  lds);
  stage_deep<AF32>(A, lda, B, ldb, 32, lds + 24576);
  stage_deep<AF32>(A, lda, B, ldb, 64, lds + 49152);
  int buf = 0;
  for (int t = 0; t < nt; ++t) {
    const int ahead = nt - 1 - t;              // staged tiles beyond t
    if (ahead >= 2)      asm volatile("s_waitcnt vmcnt(12)" ::: "memory");
    else if (ahead == 1) asm volatile("s_waitcnt vmcnt(6)"  ::: "memory");
    else                 asm volatile("s_waitcnt vmcnt(0)"  ::: "memory");
    SBAR(); SCHED0();
    __builtin_amdgcn_s_setprio(1);
    mfma_deep<AF32>(lds + buf * 24576, acc);
    __builtin_amdgcn_s_setprio(0);
    SCHED0(); SBAR();
    if (t + 3 < nt) stage_deep<AF32>(A, lda, B, ldb, (t + 3) * 32, lds + buf * 24576);
    buf = (buf == 2) ? 0 : buf + 1;
  }
}

// epilogue: local row = wm*64+mi*16+4*(lane>>4)+j ; local col = wn*64+ni*16+(lane&15)
template<int RELU>
__device__ __forceinline__ void epi_bf16(f32x4_t acc[4][4], bf16* __restrict__ C, int ldc,
                                         const float* __restrict__ bias) {
  const int lane = threadIdx.x & 63;
  const int wid  = threadIdx.x >> 6;
  const int wm = wid >> 1, wn = wid & 1;
  const int fr = lane & 15;
  const int rb = wm * 64 + 4 * (lane >> 4);
  const int cb = wn * 64 + fr;
  float bv[4];
#pragma unroll
  for (int ni = 0; ni < 4; ++ni) bv[ni] = bias[cb + ni * 16];
#pragma unroll
  for (int mi = 0; mi < 4; ++mi)
#pragma unroll
    for (int j = 0; j < 4; ++j)
#pragma unroll
      for (int ni = 0; ni < 4; ++ni) {
        float val = acc[mi][ni][j] + bv[ni];
        if (RELU) val = fmaxf(val, 0.f);
        C[(size_t)(rb + mi * 16 + j) * ldc + cb + ni * 16] = (bf16)val;
      }
}

// ---- prep: convert intra weights f32 -> bf16 ----
__device__ __forceinline__ void cp8(bf16* d, const float* s) {
  f32x4_t x0 = *(const f32x4_t*)s;
  f32x4_t x1 = *(const f32x4_t*)(s + 4);
  *(bf16x8_t*)d = cvt8(x0, x1);
}

__global__ __launch_bounds__(256) void prep_kernel(
    const float* __restrict__ w0, const float* __restrict__ w1s,
    const float* __restrict__ w2, const float* __restrict__ w3,
    bf16* __restrict__ o0, bf16* __restrict__ o1,
    bf16* __restrict__ o2, bf16* __restrict__ o3) {
  const int t = blockIdx.x * 256 + threadIdx.x;
  if (t < 65536)       { size_t i = (size_t)t * 8;            cp8(o0 + i, w0 + i); }
  else if (t < 114688) { size_t i = (size_t)(t - 65536) * 8;  cp8(o1 + i, w1s + i); }
  else if (t < 147456) { size_t i = (size_t)(t - 114688) * 8; cp8(o2 + i, w2 + i); }
  else                 { size_t i = (size_t)(t - 147456) * 8; cp8(o3 + i, w3 + i); }
}

// ---- stage A: batched intra GEMM + relu -> h[(b*4+z)*512+n] (bf16) ----
__global__ __launch_bounds__(256) void intra_kernel(
    const float* __restrict__ f0, const float* __restrict__ f1,
    const float* __restrict__ f2, const float* __restrict__ f3,
    const bf16* __restrict__ wb0, const bf16* __restrict__ wb1,
    const bf16* __restrict__ wb2, const bf16* __restrict__ wb3,
    const float* __restrict__ bb0, const float* __restrict__ bb1,
    const float* __restrict__ bb2, const float* __restrict__ bb3,
    bf16* __restrict__ hbuf) {
  __shared__ __align__(16) char lds[73728];       // 3 x 24KB
  const int bid = blockIdx.x;                     // 2048 blocks
  const int lid = (bid & 7) * 256 + (bid >> 3);   // XCD-chunked bijection
  const int x = lid & 3;                          // N-block
  const int g = lid >> 2;
  const int z = g & 3;                            // model (fast-cycling)
  const int y = g >> 2;                           // M-block (0..127)
  const float* fp; const bf16* wp; const float* bp; int K;
  switch (z) {
    case 0:  fp = f0; wp = wb0; bp = bb0; K = 1024; break;
    case 1:  fp = f1; wp = wb1; bp = bb1; K = 768;  break;
    case 2:  fp = f2; wp = wb2; bp = bb2; K = 512;  break;
    default: fp = f3; wp = wb3; bp = bb3; K = 640;  break;
  }
  f32x4_t acc[4][4];
#pragma unroll
  for (int i = 0; i < 4; ++i)
#pragma unroll
    for (int j = 0; j < 4; ++j) acc[i][j] = (f32x4_t){0.f, 0.f, 0.f, 0.f};
  core_deep3<1>(fp + (size_t)(y * 128) * K, K,
                wp + (size_t)(x * 128) * K, K, K, lds, acc);
  bf16* C = hbuf + (size_t)(y * 128) * 2048 + z * 512 + x * 128;
  epi_bf16<1>(acc, C, 2048, bp + x * 128);
}

// ---- LayerNorm over rows of 512, IN-PLACE (bf16), one wave per row ----
__global__ __launch_bounds__(256)
void ln_kernel(bf16* __restrict__ h, const float* __restrict__ g,
               const float* __restrict__ bta) {
  const int row  = blockIdx.x * 4 + (threadIdx.x >> 6);
  const int lane = threadIdx.x & 63;
  bf16* p = h + (size_t)row * 512 + lane * 8;
  const bf16x8_t x = *(const bf16x8_t*)p;
  float xf[8]; float s = 0.f, s2 = 0.f;
#pragma unroll
  for (int j = 0; j < 8; ++j) { xf[j] = (float)x[j]; s += xf[j]; s2 += xf[j] * xf[j]; }
#pragma unroll
  for (int off = 1; off < 64; off <<= 1) { s += __shfl_xor(s, off); s2 += __shfl_xor(s2, off); }
  const float mu  = s * (1.f / 512.f);
  const float var = s2 * (1.f / 512.f) - mu * mu;
  const float inv = rsqrtf(var + 1e-5f);
  f32x4_t g0 = *(const f32x4_t*)(g + lane * 8);
  f32x4_t g1 = *(const f32x4_t*)(g + lane * 8 + 4);
  f32x4_t b0 = *(const f32x4_t*)(bta + lane * 8);
  f32x4_t b1 = *(const f32x4_t*)(bta + lane * 8 + 4);
  bf16x8_t o;
#pragma unroll
  for (int j = 0; j < 4; ++j) o[j]     = (bf16)((xf[j] - mu) * inv * g0[j] + b0[j]);
#pragma unroll
  for (int j = 0; j < 4; ++j) o[4 + j] = (bf16)((xf[4 + j] - mu) * inv * g1[j] + b1[j]);
  *(bf16x8_t*)p = o;
}

// ---- stage C: fused q||v projection (65536 x 512, K=512) ----
__global__ __launch_bounds__(256) void qv_kernel(
    const bf16* __restrict__ H, const float* __restrict__ Wq,
    const float* __restrict__ Wv, const float* __restrict__ bq,
    const float* __restrict__ bv, bf16* __restrict__ qvout) {
  __shared__ __align__(16) char lds[73728];
  const int bid = blockIdx.x;                     // 2048 blocks
  const int lid = (bid & 7) * 256 + (bid >> 3);
  const int x = lid & 3, y = lid >> 2;            // y: 0..511
  const float* Wsrc = (x < 2) ? Wq : Wv;
  f32x4_t acc[4][4];
#pragma unroll
  for (int i = 0; i < 4; ++i)
#pragma unroll
    for (int j = 0; j < 4; ++j) acc[i][j] = (f32x4_t){0.f, 0.f, 0.f, 0.f};
  core_deep3<0>(H + (size_t)(y * 128) * 512, 512,
                Wsrc + (size_t)((x & 1) * 128) * 512, 512, 512, lds, acc);
  const float* bias = (x < 2) ? bq + x * 128 : bv + (x - 2) * 128;
  epi_bf16<0>(acc, qvout + (size_t)(y * 128) * 512 + x * 128, 512, bias);
}

// ---- stage E: W1 GEMM (K=1024, ldw=1028) + pred_scores rank-4 fixup ----
__global__ __launch_bounds__(256) void w1_kernel(
    const bf16* __restrict__ zb, const float* __restrict__ W1,
    const float* __restrict__ b1, const float* __restrict__ ps,
    float* __restrict__ obuf) {
  __shared__ __align__(16) char lds[73728];
  const int bid = blockIdx.x;                     // 256 blocks
  const int lid = (bid & 7) * 32 + (bid >> 3);
  const int x = lid & 1, y = lid >> 1;            // y: 0..127
  f32x4_t acc[4][4];
#pragma unroll
  for (int i = 0; i < 4; ++i)
#pragma unroll
    for (int j = 0; j < 4; ++j) acc[i][j] = (f32x4_t){0.f, 0.f, 0.f, 0.f};
  core_deep3<0>(zb + (size_t)(y * 128) * 1024, 1024,
                W1 + (size_t)(x * 128) * 1028, 1028, 1024, lds, acc);

  const int lane = threadIdx.x & 63;
  const int wid  = threadIdx.x >> 6;
  const int wm = wid >> 1, wn = wid & 1;
  const int fr = lane & 15;
  const int rb = wm * 64 + 4 * (lane >> 4);
  const int cb = x * 128 + wn * 64 + fr;          // global col
  float bv[4], wt[4][4];
#pragma unroll
  for (int ni = 0; ni < 4; ++ni) {
    bv[ni] = b1[cb + ni * 16];
#pragma unroll
    for (int m = 0; m < 4; ++m) wt[ni][m] = W1[(size_t)(cb + ni * 16) * 1028 + 1024 + m];
  }
#pragma unroll
  for (int mi = 0; mi < 4; ++mi)
#pragma unroll
    for (int j = 0; j < 4; ++j) {
      const int r = y * 128 + rb + mi * 16 + j;   // global row
      f32x4_t psv = *(const f32x4_t*)(ps + (size_t)r * 4);
#pragma unroll
      for (int ni = 0; ni < 4; ++ni) {
        float val = acc[mi][ni][j] + bv[ni]
                  + psv[0] * wt[ni][0] + psv[1] * wt[ni][1]
                  + psv[2] * wt[ni][2] + psv[3] * wt[ni][3];
        obuf[(size_t)r * 256 + cb + ni * 16] = val;
      }
    }
}

// ---- attention: 4x4 scores (k=q per source bug), softmax(-UW*(vi+vj)), z=s@v ----
__global__ __launch_bounds__(256)
void attn_kernel(const bf16* __restrict__ qv, const float* __restrict__ pvars,
                 bf16* __restrict__ z) {
  const int b    = blockIdx.x * 4 + (threadIdx.x >> 6);
  const int lane = threadIdx.x & 63;
  float qf[4][4], vf[4][4];
#pragma unroll
  for (int i = 0; i < 4; ++i) {
    const bf16* row = qv + ((size_t)b * 4 + i) * 512;
    bf16x4_t qq = *(const bf16x4_t*)(row + lane * 4);
    bf16x4_t vv = *(const bf16x4_t*)(row + 256 + lane * 4);
#pragma unroll
    for (int c = 0; c < 4; ++c) { qf[i][c] = (float)qq[c]; vf[i][c] = (float)vv[c]; }
  }
  float s[4][4];
#pragma unroll
  for (int i = 0; i < 4; ++i)
#pragma unroll
    for (int j = 0; j < 4; ++j)
      s[i][j] = qf[i][0] * qf[j][0] + qf[i][1] * qf[j][1] + qf[i][2] * qf[j][2] + qf[i][3] * qf[j][3];
#pragma unroll
  for (int off = 1; off < 64; off <<= 1)
#pragma unroll
    for (int i = 0; i < 4; ++i)
#pragma unroll
      for (int j = 0; j < 4; ++j) s[i][j] += __shfl_xor(s[i][j], off);

  float var4[4];
#pragma unroll
  for (int m = 0; m < 4; ++m) var4[m] = pvars[(size_t)b * 4 + m];
  float w[4][4];
#pragma unroll
  for (int i = 0; i < 4; ++i) {
    float t[4]; float mx = -1e30f;
#pragma unroll
    for (int j = 0; j < 4; ++j) { t[j] = s[i][j] - 0.1f * (var4[i] + var4[j]); mx = fmaxf(mx, t[j]); }
    float sum = 0.f;
#pragma unroll
    for (int j = 0; j < 4; ++j) { t[j] = expf(t[j] - mx); sum += t[j]; }
    const float is = 1.f / sum;
#pragma unroll
    for (int j = 0; j < 4; ++j) w[i][j] = t[j] * is;
  }
#pragma unroll
  for (int i = 0; i < 4; ++i) {
    bf16x4_t zo;
#pragma unroll
    for (int c = 0; c < 4; ++c) {
      float zf = w[i][0] * vf[0][c] + w[i][1] * vf[1][c] + w[i][2] * vf[2][c] + w[i][3] * vf[3][c];
      zo[c] = (bf16)zf;
    }
    *(bf16x4_t*)(z + ((size_t)b * 4 + i) * 256 + lane * 4) = zo;
  }
}

// ---- final fc (256 -> 1) + sigmoid ----
__global__ __launch_bounds__(256)
void fc_kernel(const float* __restrict__ o, const float* __restrict__ wfc,
               const float* __restrict__ bfc, float* __restrict__ out) {
  const int b    = blockIdx.x * 4 + (threadIdx.x >> 6);
  const int lane = threadIdx.x & 63;
  f32x4_t ov = *(const f32x4_t*)(o + (size_t)b * 256 + lane * 4);
  f32x4_t wv = *(const f32x4_t*)(wfc + lane * 4);
  float p = ov[0] * wv[0] + ov[1] * wv[1] + ov[2] * wv[2] + ov[3] * wv[3];
#pragma unroll
  for (int off = 1; off < 64; off <<= 1) p += __shfl_xor(p, off);
  if (lane == 0) {
    const float lg = p + bfc[0];
    out[b] = 1.f / (1.f + expf(-lg));
  }
}

extern "C" void kernel_launch(void* const* d_in, const int* in_sizes, int n_in,
                              void* d_out, int out_size, void* d_ws, size_t ws_size,
                              hipStream_t stream) {
  (void)in_sizes; (void)n_in; (void)out_size; (void)ws_size;
  const float* feat[4] = {(const float*)d_in[0], (const float*)d_in[3],
                          (const float*)d_in[6], (const float*)d_in[9]};
  const float* Wi[4]   = {(const float*)d_in[1], (const float*)d_in[4],
                          (const float*)d_in[7], (const float*)d_in[10]};
  const float* bi[4]   = {(const float*)d_in[2], (const float*)d_in[5],
                          (const float*)d_in[8], (const float*)d_in[11]};
  const float* ps  = (const float*)d_in[12];
  const float* pv  = (const float*)d_in[13];
  const float* lng = (const float*)d_in[14];
  const float* lnb = (const float*)d_in[15];
  const float* Wq  = (const float*)d_in[16];
  const float* bq  = (const float*)d_in[17];
  const float* Wv  = (const float*)d_in[20];
  const float* bvp = (const float*)d_in[21];
  const float* W1  = (const float*)d_in[22];
  const float* b1  = (const float*)d_in[23];
  const float* Wfc = (const float*)d_in[24];
  const float* bfc = (const float*)d_in[25];

  char* ws = (char*)d_ws;
  const size_t MB = 1024 * 1024;
  bf16*  hbuf  = (bf16*)ws;                        // [0,64M): h; LN in-place
  bf16*  zbuf  = (bf16*)ws;                        // [0,32M): z (after stage C)
  float* obuf  = (float*)(ws + 32 * MB);           // [32M,48M)
  bf16*  wb0   = (bf16*)(ws + 64 * MB);            // stage A only
  bf16*  wb1   = (bf16*)(ws + 65 * MB);
  bf16*  wb2   = (bf16*)(ws + 65 * MB + 786432);
  bf16*  wb3   = (bf16*)(ws + 66 * MB + 262144);
  bf16*  qvout = (bf16*)(ws + 64 * MB);            // stage C (clobbers wb*)

  hipLaunchKernelGGL(prep_kernel, dim3(736), dim3(256), 0, stream,
                     Wi[0], Wi[1], Wi[2], Wi[3], wb0, wb1, wb2, wb3);
  hipLaunchKernelGGL(intra_kernel, dim3(2048), dim3(256), 0, stream,
                     feat[0], feat[1], feat[2], feat[3],
                     wb0, wb1, wb2, wb3, bi[0], bi[1], bi[2], bi[3], hbuf);
  hipLaunchKernelGGL(ln_kernel, dim3(65536 / 4), dim3(256), 0, stream, hbuf, lng, lnb);
  hipLaunchKernelGGL(qv_kernel, dim3(2048), dim3(256), 0, stream,
                     hbuf, Wq, Wv, bq, bvp, qvout);
  hipLaunchKernelGGL(attn_kernel, dim3(16384 / 4), dim3(256), 0, stream, qvout, pv, zbuf);
  hipLaunchKernelGGL(w1_kernel, dim3(256), dim3(256), 0, stream, zbuf, W1, b1, ps, obuf);
  hipLaunchKernelGGL(fc_kernel, dim3(16384 / 4), dim3(256), 0, stream, obuf, Wfc, bfc, (float*)d_out);
}

// Round 10
// 252.585 us; speedup vs baseline: 1.1421x; 1.0149x over previous
//
#include <hip/hip_runtime.h>
#include <hip/hip_bf16.h>

// ---------------------------------------------------------------------------
// HybridFusionNetworkWithUncertainty — MI355X (gfx950), round 10
// r9 post-mortem: intra is per-CU load-PATH bound (~13 B/cy/CU incl. L2 hits);
// all schedules converge to ~150us. Fix: 128x512 intra tile (BN = full
// hidden) -> A (f32 feat) read exactly once; path-bytes 1157->578 MB.
// 512 thr / 8 waves, wave tile 128x64 (acc 8x4 frags = 128 VGPR), LDS
// dbuf 2x(16K A-f32 + 32K B-bf16) = 96KB, counted vmcnt(6).
// qv/w1/ln/attn/fc identical to r9 (passed, absmax 3.9e-3).
// ws layout (=r9): H [0,64M) (LN in-place); zbuf [0,32M); obuf [32M,48M);
// wb0-3 @64M (stage A only); qvout [64M,128M) (stage C clobbers wb*).
// ---------------------------------------------------------------------------

typedef __bf16 bf16;
typedef __bf16 bf16x4_t __attribute__((ext_vector_type(4)));
typedef __bf16 bf16x8_t __attribute__((ext_vector_type(8)));
typedef float  f32x4_t  __attribute__((ext_vector_type(4)));

__device__ __forceinline__ bf16x8_t cvt8(f32x4_t a, f32x4_t b) {
  bf16x8_t r;
  r[0] = (bf16)a[0]; r[1] = (bf16)a[1]; r[2] = (bf16)a[2]; r[3] = (bf16)a[3];
  r[4] = (bf16)b[0]; r[5] = (bf16)b[1]; r[6] = (bf16)b[2]; r[7] = (bf16)b[3];
  return r;
}

__device__ __forceinline__ void gl_lds16(const void* g, void* l) {
  __builtin_amdgcn_global_load_lds(
      (const __attribute__((address_space(1))) void*)g,
      (__attribute__((address_space(3))) void*)l, 16, 0, 0);
}

#define SBAR()   __builtin_amdgcn_s_barrier()
#define SCHED0() __builtin_amdgcn_sched_barrier(0)

// ---- bf16 tile rows of 32 bf16: chunk c of row r at c^((r>>1)&3) ----
__device__ __forceinline__ bf16x8_t frag_b16(const bf16* Ts, int row, int c0) {
  const int byte = row * 64 + ((c0 ^ ((row >> 1) & 3)) << 4);
  return *(const bf16x8_t*)((const char*)Ts + byte);
}
// ---- f32 tile rows of 32 f32: 16B chunk q of row r at q^(r&7) ----
__device__ __forceinline__ bf16x8_t frag_f32(const float* Ts, int row, int g) {
  const int p0 = (2 * g)     ^ (row & 7);
  const int p1 = (2 * g + 1) ^ (row & 7);
  f32x4_t lo = *(const f32x4_t*)((const char*)Ts + row * 128 + (p0 << 4));
  f32x4_t hi = *(const f32x4_t*)((const char*)Ts + row * 128 + (p1 << 4));
  return cvt8(lo, hi);
}

// ================= 256-thread staging (r9 cores: qv/w1) =================
__device__ __forceinline__ void stage_b16(const bf16* __restrict__ src, int ld,
                                          int k0, bf16* lds) {
  const int l = threadIdx.x & 63;
  const int w = threadIdx.x >> 6;
#pragma unroll
  for (int j = 0; j < 2; ++j) {
    const int rb = w * 32 + j * 16;
    const int r  = rb + (l >> 2);
    const int sc = (l & 3) ^ ((r >> 1) & 3);
    gl_lds16(src + (size_t)r * ld + k0 + sc * 8, (char*)lds + rb * 64);
  }
}
__device__ __forceinline__ void stage_f32(const float* __restrict__ src, int ld,
                                          int k0, float* lds) {
  const int l = threadIdx.x & 63;
  const int w = threadIdx.x >> 6;
#pragma unroll
  for (int j = 0; j < 4; ++j) {
    const int rb = w * 32 + j * 8;
    const int r  = rb + (l >> 3);
    const int q  = (l & 7) ^ (r & 7);
    gl_lds16(src + (size_t)r * ld + k0 + q * 4, (char*)lds + rb * 128);
  }
}

// ---- r9 3-deep 128x128 core (AF32=0: A bf16 + B f32) for qv/w1 ----
template<int AF32>
__device__ __forceinline__ void stage_deep(const void* A, int lda, const void* B,
                                           int ldb, int k0, char* buf) {
  if (AF32) {
    stage_f32((const float*)A, lda, k0, (float*)buf);
    stage_b16((const bf16*)B, ldb, k0, (bf16*)(buf + 16384));
  } else {
    stage_b16((const bf16*)A, lda, k0, (bf16*)buf);
    stage_f32((const float*)B, ldb, k0, (float*)(buf + 8192));
  }
}

template<int AF32>
__device__ __forceinline__ void mfma_deep(const char* buf, f32x4_t acc[4][4]) {
  const int lane = threadIdx.x & 63;
  const int wid  = threadIdx.x >> 6;
  const int wm = wid >> 1, wn = wid & 1;
  const int fr = lane & 15, g = lane >> 4;
  bf16x8_t ar[4], br[4];
  if (AF32) {
    const float* Af = (const float*)buf;
    const bf16*  Bb = (const bf16*)(buf + 16384);
#pragma unroll
    for (int mi = 0; mi < 4; ++mi) ar[mi] = frag_f32(Af, wm * 64 + mi * 16 + fr, g);
#pragma unroll
    for (int ni = 0; ni < 4; ++ni) br[ni] = frag_b16(Bb, wn * 64 + ni * 16 + fr, g);
  } else {
    const bf16*  Ab = (const bf16*)buf;
    const float* Bf = (const float*)(buf + 8192);
#pragma unroll
    for (int mi = 0; mi < 4; ++mi) ar[mi] = frag_b16(Ab, wm * 64 + mi * 16 + fr, g);
#pragma unroll
    for (int ni = 0; ni < 4; ++ni) br[ni] = frag_f32(Bf, wn * 64 + ni * 16 + fr, g);
  }
#pragma unroll
  for (int mi = 0; mi < 4; ++mi)
#pragma unroll
    for (int ni = 0; ni < 4; ++ni)
      acc[mi][ni] = __builtin_amdgcn_mfma_f32_16x16x32_bf16(ar[mi], br[ni], acc[mi][ni], 0, 0, 0);
}

template<int AF32>
__device__ __forceinline__ void core_deep3(const void* A, int lda, const void* B,
                                           int ldb, int K, char* lds,
                                           f32x4_t acc[4][4]) {
  const int nt = K >> 5;
  stage_deep<AF32>(A, lda, B, ldb, 0,  lds);
  stage_deep<AF32>(A, lda, B, ldb, 32, lds + 24576);
  stage_deep<AF32>(A, lda, B, ldb, 64, lds + 49152);
  int buf = 0;
  for (int t = 0; t < nt; ++t) {
    const int ahead = nt - 1 - t;
    if (ahead >= 2)      asm volatile("s_waitcnt vmcnt(12)" ::: "memory");
    else if (ahead == 1) asm volatile("s_waitcnt vmcnt(6)"  ::: "memory");
    else                 asm volatile("s_waitcnt vmcnt(0)"  ::: "memory");
    SBAR(); SCHED0();
    __builtin_amdgcn_s_setprio(1);
    mfma_deep<AF32>(lds + buf * 24576, acc);
    __builtin_amdgcn_s_setprio(0);
    SCHED0(); SBAR();
    if (t + 3 < nt) stage_deep<AF32>(A, lda, B, ldb, (t + 3) * 32, lds + buf * 24576);
    buf = (buf == 2) ? 0 : buf + 1;
  }
}

template<int RELU>
__device__ __forceinline__ void epi_bf16(f32x4_t acc[4][4], bf16* __restrict__ C, int ldc,
                                         const float* __restrict__ bias) {
  const int lane = threadIdx.x & 63;
  const int wid  = threadIdx.x >> 6;
  const int wm = wid >> 1, wn = wid & 1;
  const int fr = lane & 15;
  const int rb = wm * 64 + 4 * (lane >> 4);
  const int cb = wn * 64 + fr;
  float bv[4];
#pragma unroll
  for (int ni = 0; ni < 4; ++ni) bv[ni] = bias[cb + ni * 16];
#pragma unroll
  for (int mi = 0; mi < 4; ++mi)
#pragma unroll
    for (int j = 0; j < 4; ++j)
#pragma unroll
      for (int ni = 0; ni < 4; ++ni) {
        float val = acc[mi][ni][j] + bv[ni];
        if (RELU) val = fmaxf(val, 0.f);
        C[(size_t)(rb + mi * 16 + j) * ldc + cb + ni * 16] = (bf16)val;
      }
}

// ================= 512-thread intra (128x512 tile) =================
// A f32 [128][32] (16KB), B bf16 [512][32] (32KB); 6 vm-ops/thread/tile.
__device__ __forceinline__ void stage_f32_512(const float* __restrict__ src, int ld,
                                              int k0, float* lds) {
  const int l = threadIdx.x & 63;
  const int w = threadIdx.x >> 6;                 // 0..7
#pragma unroll
  for (int j = 0; j < 2; ++j) {
    const int rb = w * 16 + j * 8;
    const int r  = rb + (l >> 3);
    const int q  = (l & 7) ^ (r & 7);
    gl_lds16(src + (size_t)r * ld + k0 + q * 4, (char*)lds + rb * 128);
  }
}
__device__ __forceinline__ void stage_b16_512(const bf16* __restrict__ src, int ld,
                                              int k0, bf16* lds) {
  const int l = threadIdx.x & 63;
  const int w = threadIdx.x >> 6;
#pragma unroll
  for (int j = 0; j < 4; ++j) {
    const int rb = w * 64 + j * 16;
    const int r  = rb + (l >> 2);
    const int sc = (l & 3) ^ ((r >> 1) & 3);
    gl_lds16(src + (size_t)r * ld + k0 + sc * 8, (char*)lds + rb * 64);
  }
}

__device__ __forceinline__ void mfma_512(const char* buf, f32x4_t acc[8][4]) {
  const int lane = threadIdx.x & 63;
  const int wn   = threadIdx.x >> 6;              // 0..7 -> cols wn*64
  const int fr = lane & 15, g = lane >> 4;
  const float* Af = (const float*)buf;
  const bf16*  Bb = (const bf16*)(buf + 16384);
  bf16x8_t ar[8], br[4];
#pragma unroll
  for (int mi = 0; mi < 8; ++mi) ar[mi] = frag_f32(Af, mi * 16 + fr, g);
#pragma unroll
  for (int ni = 0; ni < 4; ++ni) br[ni] = frag_b16(Bb, wn * 64 + ni * 16 + fr, g);
#pragma unroll
  for (int mi = 0; mi < 8; ++mi)
#pragma unroll
    for (int ni = 0; ni < 4; ++ni)
      acc[mi][ni] = __builtin_amdgcn_mfma_f32_16x16x32_bf16(ar[mi], br[ni], acc[mi][ni], 0, 0, 0);
}

__global__ __launch_bounds__(512, 2) void intra_kernel(
    const float* __restrict__ f0, const float* __restrict__ f1,
    const float* __restrict__ f2, const float* __restrict__ f3,
    const bf16* __restrict__ wb0, const bf16* __restrict__ wb1,
    const bf16* __restrict__ wb2, const bf16* __restrict__ wb3,
    const float* __restrict__ bb0, const float* __restrict__ bb1,
    const float* __restrict__ bb2, const float* __restrict__ bb3,
    bf16* __restrict__ hbuf) {
  __shared__ __align__(16) char lds[98304];       // 2 x 48KB (A16K + B32K)
  const int bid = blockIdx.x;                     // 512 blocks
  const int lid = (bid & 7) * 64 + (bid >> 3);    // XCD-chunked bijection
  const int z = lid & 3;                          // model
  const int y = lid >> 2;                         // M-block (0..127)
  const float* fp; const bf16* wp; const float* bp; int K;
  switch (z) {
    case 0:  fp = f0; wp = wb0; bp = bb0; K = 1024; break;
    case 1:  fp = f1; wp = wb1; bp = bb1; K = 768;  break;
    case 2:  fp = f2; wp = wb2; bp = bb2; K = 512;  break;
    default: fp = f3; wp = wb3; bp = bb3; K = 640;  break;
  }
  const float* A = fp + (size_t)(y * 128) * K;
  const bf16*  B = wp;                            // all 512 rows

  f32x4_t acc[8][4];
#pragma unroll
  for (int i = 0; i < 8; ++i)
#pragma unroll
    for (int j = 0; j < 4; ++j) acc[i][j] = (f32x4_t){0.f, 0.f, 0.f, 0.f};

  const int nt = K >> 5;
  char* buf0 = lds;
  char* buf1 = lds + 49152;
  stage_f32_512(A, K, 0, (float*)buf0);
  stage_b16_512(B, K, 0, (bf16*)(buf0 + 16384));
  stage_f32_512(A, K, 32, (float*)buf1);
  stage_b16_512(B, K, 32, (bf16*)(buf1 + 16384));
  for (int t = 0; t < nt; ++t) {
    char* cur = (t & 1) ? buf1 : buf0;
    if (t + 1 < nt) asm volatile("s_waitcnt vmcnt(6)" ::: "memory");
    else            asm volatile("s_waitcnt vmcnt(0)" ::: "memory");
    SBAR(); SCHED0();
    __builtin_amdgcn_s_setprio(1);
    mfma_512(cur, acc);
    __builtin_amdgcn_s_setprio(0);
    SCHED0(); SBAR();
    if (t + 2 < nt) {
      stage_f32_512(A, K, (t + 2) * 32, (float*)cur);
      stage_b16_512(B, K, (t + 2) * 32, (bf16*)(cur + 16384));
    }
  }

  // epilogue: row = mi*16 + 4*(lane>>4)+j ; col = wn*64 + ni*16 + (lane&15)
  const int lane = threadIdx.x & 63;
  const int wn   = threadIdx.x >> 6;
  const int fr = lane & 15;
  const int rb = 4 * (lane >> 4);
  float bv[4];
#pragma unroll
  for (int ni = 0; ni < 4; ++ni) bv[ni] = bp[wn * 64 + ni * 16 + fr];
  bf16* C = hbuf + (size_t)(y * 128) * 2048 + z * 512;
#pragma unroll
  for (int mi = 0; mi < 8; ++mi)
#pragma unroll
    for (int j = 0; j < 4; ++j) {
      const int row = mi * 16 + rb + j;
#pragma unroll
      for (int ni = 0; ni < 4; ++ni) {
        float val = fmaxf(acc[mi][ni][j] + bv[ni], 0.f);
        C[(size_t)row * 2048 + wn * 64 + ni * 16 + fr] = (bf16)val;
      }
    }
}

// ---- prep: convert intra weights f32 -> bf16 ----
__device__ __forceinline__ void cp8(bf16* d, const float* s) {
  f32x4_t x0 = *(const f32x4_t*)s;
  f32x4_t x1 = *(const f32x4_t*)(s + 4);
  *(bf16x8_t*)d = cvt8(x0, x1);
}

__global__ __launch_bounds__(256) void prep_kernel(
    const float* __restrict__ w0, const float* __restrict__ w1s,
    const float* __restrict__ w2, const float* __restrict__ w3,
    bf16* __restrict__ o0, bf16* __restrict__ o1,
    bf16* __restrict__ o2, bf16* __restrict__ o3) {
  const int t = blockIdx.x * 256 + threadIdx.x;
  if (t < 65536)       { size_t i = (size_t)t * 8;            cp8(o0 + i, w0 + i); }
  else if (t < 114688) { size_t i = (size_t)(t - 65536) * 8;  cp8(o1 + i, w1s + i); }
  else if (t < 147456) { size_t i = (size_t)(t - 114688) * 8; cp8(o2 + i, w2 + i); }
  else                 { size_t i = (size_t)(t - 147456) * 8; cp8(o3 + i, w3 + i); }
}

// ---- LayerNorm over rows of 512, IN-PLACE (bf16), one wave per row ----
__global__ __launch_bounds__(256)
void ln_kernel(bf16* __restrict__ h, const float* __restrict__ g,
               const float* __restrict__ bta) {
  const int row  = blockIdx.x * 4 + (threadIdx.x >> 6);
  const int lane = threadIdx.x & 63;
  bf16* p = h + (size_t)row * 512 + lane * 8;
  const bf16x8_t x = *(const bf16x8_t*)p;
  float xf[8]; float s = 0.f, s2 = 0.f;
#pragma unroll
  for (int j = 0; j < 8; ++j) { xf[j] = (float)x[j]; s += xf[j]; s2 += xf[j] * xf[j]; }
#pragma unroll
  for (int off = 1; off < 64; off <<= 1) { s += __shfl_xor(s, off); s2 += __shfl_xor(s2, off); }
  const float mu  = s * (1.f / 512.f);
  const float var = s2 * (1.f / 512.f) - mu * mu;
  const float inv = rsqrtf(var + 1e-5f);
  f32x4_t g0 = *(const f32x4_t*)(g + lane * 8);
  f32x4_t g1 = *(const f32x4_t*)(g + lane * 8 + 4);
  f32x4_t b0 = *(const f32x4_t*)(bta + lane * 8);
  f32x4_t b1 = *(const f32x4_t*)(bta + lane * 8 + 4);
  bf16x8_t o;
#pragma unroll
  for (int j = 0; j < 4; ++j) o[j]     = (bf16)((xf[j] - mu) * inv * g0[j] + b0[j]);
#pragma unroll
  for (int j = 0; j < 4; ++j) o[4 + j] = (bf16)((xf[4 + j] - mu) * inv * g1[j] + b1[j]);
  *(bf16x8_t*)p = o;
}

// ---- stage C: fused q||v projection (65536 x 512, K=512) ----
__global__ __launch_bounds__(256) void qv_kernel(
    const bf16* __restrict__ H, const float* __restrict__ Wq,
    const float* __restrict__ Wv, const float* __restrict__ bq,
    const float* __restrict__ bv, bf16* __restrict__ qvout) {
  __shared__ __align__(16) char lds[73728];
  const int bid = blockIdx.x;                     // 2048 blocks
  const int lid = (bid & 7) * 256 + (bid >> 3);
  const int x = lid & 3, y = lid >> 2;            // y: 0..511
  const float* Wsrc = (x < 2) ? Wq : Wv;
  f32x4_t acc[4][4];
#pragma unroll
  for (int i = 0; i < 4; ++i)
#pragma unroll
    for (int j = 0; j < 4; ++j) acc[i][j] = (f32x4_t){0.f, 0.f, 0.f, 0.f};
  core_deep3<0>(H + (size_t)(y * 128) * 512, 512,
                Wsrc + (size_t)((x & 1) * 128) * 512, 512, 512, lds, acc);
  const float* bias = (x < 2) ? bq + x * 128 : bv + (x - 2) * 128;
  epi_bf16<0>(acc, qvout + (size_t)(y * 128) * 512 + x * 128, 512, bias);
}

// ---- stage E: W1 GEMM (K=1024, ldw=1028) + pred_scores rank-4 fixup ----
__global__ __launch_bounds__(256) void w1_kernel(
    const bf16* __restrict__ zb, const float* __restrict__ W1,
    const float* __restrict__ b1, const float* __restrict__ ps,
    float* __restrict__ obuf) {
  __shared__ __align__(16) char lds[73728];
  const int bid = blockIdx.x;                     // 256 blocks
  const int lid = (bid & 7) * 32 + (bid >> 3);
  const int x = lid & 1, y = lid >> 1;            // y: 0..127
  f32x4_t acc[4][4];
#pragma unroll
  for (int i = 0; i < 4; ++i)
#pragma unroll
    for (int j = 0; j < 4; ++j) acc[i][j] = (f32x4_t){0.f, 0.f, 0.f, 0.f};
  core_deep3<0>(zb + (size_t)(y * 128) * 1024, 1024,
                W1 + (size_t)(x * 128) * 1028, 1028, 1024, lds, acc);

  const int lane = threadIdx.x & 63;
  const int wid  = threadIdx.x >> 6;
  const int wm = wid >> 1, wn = wid & 1;
  const int fr = lane & 15;
  const int rb = wm * 64 + 4 * (lane >> 4);
  const int cb = x * 128 + wn * 64 + fr;          // global col
  float bv[4], wt[4][4];
#pragma unroll
  for (int ni = 0; ni < 4; ++ni) {
    bv[ni] = b1[cb + ni * 16];
#pragma unroll
    for (int m = 0; m < 4; ++m) wt[ni][m] = W1[(size_t)(cb + ni * 16) * 1028 + 1024 + m];
  }
#pragma unroll
  for (int mi = 0; mi < 4; ++mi)
#pragma unroll
    for (int j = 0; j < 4; ++j) {
      const int r = y * 128 + rb + mi * 16 + j;   // global row
      f32x4_t psv = *(const f32x4_t*)(ps + (size_t)r * 4);
#pragma unroll
      for (int ni = 0; ni < 4; ++ni) {
        float val = acc[mi][ni][j] + bv[ni]
                  + psv[0] * wt[ni][0] + psv[1] * wt[ni][1]
                  + psv[2] * wt[ni][2] + psv[3] * wt[ni][3];
        obuf[(size_t)r * 256 + cb + ni * 16] = val;
      }
    }
}

// ---- attention: 4x4 scores (k=q per source bug), softmax(-UW*(vi+vj)), z=s@v ----
__global__ __launch_bounds__(256)
void attn_kernel(const bf16* __restrict__ qv, const float* __restrict__ pvars,
                 bf16* __restrict__ z) {
  const int b    = blockIdx.x * 4 + (threadIdx.x >> 6);
  const int lane = threadIdx.x & 63;
  float qf[4][4], vf[4][4];
#pragma unroll
  for (int i = 0; i < 4; ++i) {
    const bf16* row = qv + ((size_t)b * 4 + i) * 512;
    bf16x4_t qq = *(const bf16x4_t*)(row + lane * 4);
    bf16x4_t vv = *(const bf16x4_t*)(row + 256 + lane * 4);
#pragma unroll
    for (int c = 0; c < 4; ++c) { qf[i][c] = (float)qq[c]; vf[i][c] = (float)vv[c]; }
  }
  float s[4][4];
#pragma unroll
  for (int i = 0; i < 4; ++i)
#pragma unroll
    for (int j = 0; j < 4; ++j)
      s[i][j] = qf[i][0] * qf[j][0] + qf[i][1] * qf[j][1] + qf[i][2] * qf[j][2] + qf[i][3] * qf[j][3];
#pragma unroll
  for (int off = 1; off < 64; off <<= 1)
#pragma unroll
    for (int i = 0; i < 4; ++i)
#pragma unroll
      for (int j = 0; j < 4; ++j) s[i][j] += __shfl_xor(s[i][j], off);

  float var4[4];
#pragma unroll
  for (int m = 0; m < 4; ++m) var4[m] = pvars[(size_t)b * 4 + m];
  float w[4][4];
#pragma unroll
  for (int i = 0; i < 4; ++i) {
    float t[4]; float mx = -1e30f;
#pragma unroll
    for (int j = 0; j < 4; ++j) { t[j] = s[i][j] - 0.1f * (var4[i] + var4[j]); mx = fmaxf(mx, t[j]); }
    float sum = 0.f;
#pragma unroll
    for (int j = 0; j < 4; ++j) { t[j] = expf(t[j] - mx); sum += t[j]; }
    const float is = 1.f / sum;
#pragma unroll
    for (int j = 0; j < 4; ++j) w[i][j] = t[j] * is;
  }
#pragma unroll
  for (int i = 0; i < 4; ++i) {
    bf16x4_t zo;
#pragma unroll
    for (int c = 0; c < 4; ++c) {
      float zf = w[i][0] * vf[0][c] + w[i][1] * vf[1][c] + w[i][2] * vf[2][c] + w[i][3] * vf[3][c];
      zo[c] = (bf16)zf;
    }
    *(bf16x4_t*)(z + ((size_t)b * 4 + i) * 256 + lane * 4) = zo;
  }
}

// ---- final fc (256 -> 1) + sigmoid ----
__global__ __launch_bounds__(256)
void fc_kernel(const float* __restrict__ o, const float* __restrict__ wfc,
               const float* __restrict__ bfc, float* __restrict__ out) {
  const int b    = blockIdx.x * 4 + (threadIdx.x >> 6);
  const int lane = threadIdx.x & 63;
  f32x4_t ov = *(const f32x4_t*)(o + (size_t)b * 256 + lane * 4);
  f32x4_t wv = *(const f32x4_t*)(wfc + lane * 4);
  float p = ov[0] * wv[0] + ov[1] * wv[1] + ov[2] * wv[2] + ov[3] * wv[3];
#pragma unroll
  for (int off = 1; off < 64; off <<= 1) p += __shfl_xor(p, off);
  if (lane == 0) {
    const float lg = p + bfc[0];
    out[b] = 1.f / (1.f + expf(-lg));
  }
}

extern "C" void kernel_launch(void* const* d_in, const int* in_sizes, int n_in,
                              void* d_out, int out_size, void* d_ws, size_t ws_size,
                              hipStream_t stream) {
  (void)in_sizes; (void)n_in; (void)out_size; (void)ws_size;
  const float* feat[4] = {(const float*)d_in[0], (const float*)d_in[3],
                          (const float*)d_in[6], (const float*)d_in[9]};
  const float* Wi[4]   = {(const float*)d_in[1], (const float*)d_in[4],
                          (const float*)d_in[7], (const float*)d_in[10]};
  const float* bi[4]   = {(const float*)d_in[2], (const float*)d_in[5],
                          (const float*)d_in[8], (const float*)d_in[11]};
  const float* ps  = (const float*)d_in[12];
  const float* pv  = (const float*)d_in[13];
  const float* lng = (const float*)d_in[14];
  const float* lnb = (const float*)d_in[15];
  const float* Wq  = (const float*)d_in[16];
  const float* bq  = (const float*)d_in[17];
  const float* Wv  = (const float*)d_in[20];
  const float* bvp = (const float*)d_in[21];
  const float* W1  = (const float*)d_in[22];
  const float* b1  = (const float*)d_in[23];
  const float* Wfc = (const float*)d_in[24];
  const float* bfc = (const float*)d_in[25];

  char* ws = (char*)d_ws;
  const size_t MB = 1024 * 1024;
  bf16*  hbuf  = (bf16*)ws;                        // [0,64M): h; LN in-place
  bf16*  zbuf  = (bf16*)ws;                        // [0,32M): z (after stage C)
  float* obuf  = (float*)(ws + 32 * MB);           // [32M,48M)
  bf16*  wb0   = (bf16*)(ws + 64 * MB);            // stage A only
  bf16*  wb1   = (bf16*)(ws + 65 * MB);
  bf16*  wb2   = (bf16*)(ws + 65 * MB + 786432);
  bf16*  wb3   = (bf16*)(ws + 66 * MB + 262144);
  bf16*  qvout = (bf16*)(ws + 64 * MB);            // stage C (clobbers wb*)

  hipLaunchKernelGGL(prep_kernel, dim3(736), dim3(256), 0, stream,
                     Wi[0], Wi[1], Wi[2], Wi[3], wb0, wb1, wb2, wb3);
  hipLaunchKernelGGL(intra_kernel, dim3(512), dim3(512), 0, stream,
                     feat[0], feat[1], feat[2], feat[3],
                     wb0, wb1, wb2, wb3, bi[0], bi[1], bi[2], bi[3], hbuf);
  hipLaunchKernelGGL(ln_kernel, dim3(65536 / 4), dim3(256), 0, stream, hbuf, lng, lnb);
  hipLaunchKernelGGL(qv_kernel, dim3(2048), dim3(256), 0, stream,
                     hbuf, Wq, Wv, bq, bvp, qvout);
  hipLaunchKernelGGL(attn_kernel, dim3(16384 / 4), dim3(256), 0, stream, qvout, pv, zbuf);
  hipLaunchKernelGGL(w1_kernel, dim3(256), dim3(256), 0, stream, zbuf, W1, b1, ps, obuf);
  hipLaunchKernelGGL(fc_kernel, dim3(16384 / 4), dim3(256), 0, stream, obuf, Wfc, bfc, (float*)d_out);
}

// Round 12
// 237.922 us; speedup vs baseline: 1.2125x; 1.0616x over previous
//
#include <hip/hip_runtime.h>
#include <hip/hip_bf16.h>

// ---------------------------------------------------------------------------
// HybridFusionNetworkWithUncertainty — MI355X (gfx950), round 12
// r11 failed; prime suspect = 144KB/120KB workgroup LDS (silent launch fail).
// r12 bisect: keep r11's audited logic (fused LN epilogue, balanced z^2
// pairing, 2x4 wave grid) but restore the r10-PROVEN 96KB 2-deep staging
// (vmcnt(6)/(0), stage-after-2nd-barrier). qv/w1/attn/fc/prep = r10 verbatim.
// ws: H [0,64M) ; zbuf [0,32M) ; obuf [32M,48M) ; wb0-3 @64M (intra only) ;
//     qvout [64M,128M) (stage C clobbers wb*).
// ---------------------------------------------------------------------------

typedef __bf16 bf16;
typedef __bf16 bf16x4_t __attribute__((ext_vector_type(4)));
typedef __bf16 bf16x8_t __attribute__((ext_vector_type(8)));
typedef float  f32x4_t  __attribute__((ext_vector_type(4)));

__device__ __forceinline__ bf16x8_t cvt8(f32x4_t a, f32x4_t b) {
  bf16x8_t r;
  r[0] = (bf16)a[0]; r[1] = (bf16)a[1]; r[2] = (bf16)a[2]; r[3] = (bf16)a[3];
  r[4] = (bf16)b[0]; r[5] = (bf16)b[1]; r[6] = (bf16)b[2]; r[7] = (bf16)b[3];
  return r;
}

__device__ __forceinline__ void gl_lds16(const void* g, void* l) {
  __builtin_amdgcn_global_load_lds(
      (const __attribute__((address_space(1))) void*)g,
      (__attribute__((address_space(3))) void*)l, 16, 0, 0);
}

#define SBAR()   __builtin_amdgcn_s_barrier()
#define SCHED0() __builtin_amdgcn_sched_barrier(0)

// bf16 tile rows of 32 bf16 (64B): chunk c of row r at c^((r>>1)&3)
__device__ __forceinline__ bf16x8_t frag_b16(const bf16* Ts, int row, int c0) {
  const int byte = row * 64 + ((c0 ^ ((row >> 1) & 3)) << 4);
  return *(const bf16x8_t*)((const char*)Ts + byte);
}
// f32 tile rows of 32 f32 (128B): 16B chunk q of row r at q^(r&7)
__device__ __forceinline__ bf16x8_t frag_f32(const float* Ts, int row, int g) {
  const int p0 = (2 * g)     ^ (row & 7);
  const int p1 = (2 * g + 1) ^ (row & 7);
  f32x4_t lo = *(const f32x4_t*)((const char*)Ts + row * 128 + (p0 << 4));
  f32x4_t hi = *(const f32x4_t*)((const char*)Ts + row * 128 + (p1 << 4));
  return cvt8(lo, hi);
}

// ---- 512-thread staging (r10-proven) ----
// A f32 [128][32] (16KB): 2 gl_lds/thread
__device__ __forceinline__ void stage_f32_512(const float* __restrict__ src, int ld,
                                              int k0, float* lds) {
  const int l = threadIdx.x & 63;
  const int w = threadIdx.x >> 6;
#pragma unroll
  for (int j = 0; j < 2; ++j) {
    const int rb = w * 16 + j * 8;
    const int r  = rb + (l >> 3);
    const int q  = (l & 7) ^ (r & 7);
    gl_lds16(src + (size_t)r * ld + k0 + q * 4, (char*)lds + rb * 128);
  }
}
// bf16 [512][32] (32KB): 4 gl_lds/thread
__device__ __forceinline__ void stage_b512x32(const bf16* __restrict__ src, int ld,
                                              int k0, bf16* lds) {
  const int l = threadIdx.x & 63;
  const int w = threadIdx.x >> 6;
#pragma unroll
  for (int j = 0; j < 4; ++j) {
    const int rb = w * 64 + j * 16;
    const int r  = rb + (l >> 2);
    const int sc = (l & 3) ^ ((r >> 1) & 3);
    gl_lds16(src + (size_t)r * ld + k0 + sc * 8, (char*)lds + rb * 64);
  }
}

// ---- stage A (fused): intra GEMM 128x512 + relu + LN -> H ----
// 2-deep, 2 x 48KB = 96KB LDS (r10-proven size & wait discipline).
__global__ __launch_bounds__(512) void intra_ln_kernel(
    const float* __restrict__ f0, const float* __restrict__ f1,
    const float* __restrict__ f2, const float* __restrict__ f3,
    const bf16* __restrict__ wb0, const bf16* __restrict__ wb1,
    const bf16* __restrict__ wb2, const bf16* __restrict__ wb3,
    const float* __restrict__ bb0, const float* __restrict__ bb1,
    const float* __restrict__ bb2, const float* __restrict__ bb3,
    const float* __restrict__ lng, const float* __restrict__ lnb,
    bf16* __restrict__ Hout) {
  __shared__ __align__(16) char lds[98304];        // 2 x (A16K + B32K)
  const int bid  = blockIdx.x;                     // 512 blocks
  const int p    = bid & 255, half = bid >> 8;
  const int px   = (p & 7) * 32 + (p >> 3);        // XCD-chunked bijection
  int z = px & 3, y = px >> 2;                     // y 0..63
  if (half) { z ^= 2; y += 64; }                   // complementary K pairing
  const float* fp; const bf16* wp; const float* bp; int K;
  switch (z) {
    case 0:  fp = f0; wp = wb0; bp = bb0; K = 1024; break;
    case 1:  fp = f1; wp = wb1; bp = bb1; K = 768;  break;
    case 2:  fp = f2; wp = wb2; bp = bb2; K = 512;  break;
    default: fp = f3; wp = wb3; bp = bb3; K = 640;  break;
  }
  const float* A = fp + (size_t)(y * 128) * K;
  const bf16*  B = wp;
  const int tid = threadIdx.x;
  const int lane = tid & 63;
  const int wid  = tid >> 6;                       // 0..7
  const int wm = wid >> 2, wn = wid & 3;           // wave = 64 rows x 128 cols
  const int fr = lane & 15, g = lane >> 4;

  f32x4_t acc[4][8];
#pragma unroll
  for (int i = 0; i < 4; ++i)
#pragma unroll
    for (int j = 0; j < 8; ++j) acc[i][j] = (f32x4_t){0.f, 0.f, 0.f, 0.f};

  const int nt = K >> 5;                           // >= 16
  char* buf0 = lds;
  char* buf1 = lds + 49152;
  auto stage = [&](int t, char* buf) {
    stage_f32_512(A, K, t * 32, (float*)buf);
    stage_b512x32(B, K, t * 32, (bf16*)(buf + 16384));
  };
  stage(0, buf0);
  stage(1, buf1);
  for (int t = 0; t < nt; ++t) {
    char* cur = (t & 1) ? buf1 : buf0;
    if (t + 1 < nt) asm volatile("s_waitcnt vmcnt(6)" ::: "memory");
    else            asm volatile("s_waitcnt vmcnt(0)" ::: "memory");
    SBAR(); SCHED0();
    __builtin_amdgcn_s_setprio(1);
    {
      const float* Af = (const float*)cur;
      const bf16*  Bb = (const bf16*)(cur + 16384);
      bf16x8_t ar[4], br[8];
#pragma unroll
      for (int mi = 0; mi < 4; ++mi) ar[mi] = frag_f32(Af, wm * 64 + mi * 16 + fr, g);
#pragma unroll
      for (int ni = 0; ni < 8; ++ni) br[ni] = frag_b16(Bb, wn * 128 + ni * 16 + fr, g);
#pragma unroll
      for (int mi = 0; mi < 4; ++mi)
#pragma unroll
        for (int ni = 0; ni < 8; ++ni)
          acc[mi][ni] = __builtin_amdgcn_mfma_f32_16x16x32_bf16(ar[mi], br[ni], acc[mi][ni], 0, 0, 0);
    }
    __builtin_amdgcn_s_setprio(0);
    SCHED0(); SBAR();
    if (t + 2 < nt) stage(t + 2, cur);
  }

  // ---- fused LayerNorm epilogue (stats in f32) ----
  float* part  = (float*)lds;                      // [8][64][2] = 4KB
  float* muinv = (float*)(lds + 4096);             // [128][2]   = 1KB
  float bv8[8];
#pragma unroll
  for (int ni = 0; ni < 8; ++ni) bv8[ni] = bp[wn * 128 + ni * 16 + fr];
  // pass 1: per-row partial sums over this wave's 128 cols
#pragma unroll
  for (int mi = 0; mi < 4; ++mi)
#pragma unroll
    for (int j = 0; j < 4; ++j) {
      float s = 0.f, s2 = 0.f;
#pragma unroll
      for (int ni = 0; ni < 8; ++ni) {
        float v = fmaxf(acc[mi][ni][j] + bv8[ni], 0.f);
        s += v; s2 += v * v;
      }
#pragma unroll
      for (int off = 1; off < 16; off <<= 1) {
        s += __shfl_xor(s, off); s2 += __shfl_xor(s2, off);
      }
      if (fr == 0) {
        const int rl = mi * 16 + 4 * g + j;        // 0..63
        part[(wid * 64 + rl) * 2]     = s;
        part[(wid * 64 + rl) * 2 + 1] = s2;
      }
    }
  __syncthreads();
  if (tid < 128) {
    const int wmt = tid >> 6, rl = tid & 63;
    float s = 0.f, s2 = 0.f;
#pragma unroll
    for (int q = 0; q < 4; ++q) {
      s  += part[((wmt * 4 + q) * 64 + rl) * 2];
      s2 += part[((wmt * 4 + q) * 64 + rl) * 2 + 1];
    }
    const float mu  = s * (1.f / 512.f);
    const float var = s2 * (1.f / 512.f) - mu * mu;
    muinv[tid * 2]     = mu;
    muinv[tid * 2 + 1] = rsqrtf(var + 1e-5f);
  }
  __syncthreads();
  float gg[8], be[8];
#pragma unroll
  for (int ni = 0; ni < 8; ++ni) {
    const int col = wn * 128 + ni * 16 + fr;
    gg[ni] = lng[col]; be[ni] = lnb[col];
  }
#pragma unroll
  for (int mi = 0; mi < 4; ++mi)
#pragma unroll
    for (int j = 0; j < 4; ++j) {
      const int row = wm * 64 + mi * 16 + 4 * g + j;
      const float mu  = muinv[row * 2];
      const float inv = muinv[row * 2 + 1];
      bf16* hp = Hout + (size_t)(y * 128 + row) * 2048 + z * 512;
#pragma unroll
      for (int ni = 0; ni < 8; ++ni) {
        float v = fmaxf(acc[mi][ni][j] + bv8[ni], 0.f);
        hp[wn * 128 + ni * 16 + fr] = (bf16)((v - mu) * inv * gg[ni] + be[ni]);
      }
    }
}

// ================= 256-thread helpers (qv/w1, r10-verified) =================
__device__ __forceinline__ void stage_b16(const bf16* __restrict__ src, int ld,
                                          int k0, bf16* lds) {
  const int l = threadIdx.x & 63;
  const int w = threadIdx.x >> 6;
#pragma unroll
  for (int j = 0; j < 2; ++j) {
    const int rb = w * 32 + j * 16;
    const int r  = rb + (l >> 2);
    const int sc = (l & 3) ^ ((r >> 1) & 3);
    gl_lds16(src + (size_t)r * ld + k0 + sc * 8, (char*)lds + rb * 64);
  }
}
__device__ __forceinline__ void stage_f32(const float* __restrict__ src, int ld,
                                          int k0, float* lds) {
  const int l = threadIdx.x & 63;
  const int w = threadIdx.x >> 6;
#pragma unroll
  for (int j = 0; j < 4; ++j) {
    const int rb = w * 32 + j * 8;
    const int r  = rb + (l >> 3);
    const int q  = (l & 7) ^ (r & 7);
    gl_lds16(src + (size_t)r * ld + k0 + q * 4, (char*)lds + rb * 128);
  }
}
__device__ __forceinline__ void mfma_deep0(const char* buf, f32x4_t acc[4][4]) {
  const int lane = threadIdx.x & 63;
  const int wid  = threadIdx.x >> 6;
  const int wm = wid >> 1, wn = wid & 1;
  const int fr = lane & 15, g = lane >> 4;
  const bf16*  Ab = (const bf16*)buf;
  const float* Bf = (const float*)(buf + 8192);
  bf16x8_t ar[4], br[4];
#pragma unroll
  for (int mi = 0; mi < 4; ++mi) ar[mi] = frag_b16(Ab, wm * 64 + mi * 16 + fr, g);
#pragma unroll
  for (int ni = 0; ni < 4; ++ni) br[ni] = frag_f32(Bf, wn * 64 + ni * 16 + fr, g);
#pragma unroll
  for (int mi = 0; mi < 4; ++mi)
#pragma unroll
    for (int ni = 0; ni < 4; ++ni)
      acc[mi][ni] = __builtin_amdgcn_mfma_f32_16x16x32_bf16(ar[mi], br[ni], acc[mi][ni], 0, 0, 0);
}
__device__ __forceinline__ void core_deep3_0(const void* A, int lda, const void* B,
                                             int ldb, int K, char* lds,
                                             f32x4_t acc[4][4]) {
  const int nt = K >> 5;
  auto stage = [&](int t, char* buf) {
    stage_b16((const bf16*)A, lda, t * 32, (bf16*)buf);
    stage_f32((const float*)B, ldb, t * 32, (float*)(buf + 8192));
  };
  stage(0, lds); stage(1, lds + 24576); stage(2, lds + 49152);
  int bsel = 0;
  for (int t = 0; t < nt; ++t) {
    const int ahead = nt - 1 - t;
    if (ahead >= 2)      asm volatile("s_waitcnt vmcnt(12)" ::: "memory");
    else if (ahead == 1) asm volatile("s_waitcnt vmcnt(6)"  ::: "memory");
    else                 asm volatile("s_waitcnt vmcnt(0)"  ::: "memory");
    SBAR(); SCHED0();
    __builtin_amdgcn_s_setprio(1);
    mfma_deep0(lds + bsel * 24576, acc);
    __builtin_amdgcn_s_setprio(0);
    SCHED0(); SBAR();
    if (t + 3 < nt) stage(t + 3, lds + bsel * 24576);
    bsel = (bsel == 2) ? 0 : bsel + 1;
  }
}
template<int RELU>
__device__ __forceinline__ void epi_bf16(f32x4_t acc[4][4], bf16* __restrict__ C, int ldc,
                                         const float* __restrict__ bias) {
  const int lane = threadIdx.x & 63;
  const int wid  = threadIdx.x >> 6;
  const int wm = wid >> 1, wn = wid & 1;
  const int fr = lane & 15;
  const int rb = wm * 64 + 4 * (lane >> 4);
  const int cb = wn * 64 + fr;
  float bv[4];
#pragma unroll
  for (int ni = 0; ni < 4; ++ni) bv[ni] = bias[cb + ni * 16];
#pragma unroll
  for (int mi = 0; mi < 4; ++mi)
#pragma unroll
    for (int j = 0; j < 4; ++j)
#pragma unroll
      for (int ni = 0; ni < 4; ++ni) {
        float val = acc[mi][ni][j] + bv[ni];
        if (RELU) val = fmaxf(val, 0.f);
        C[(size_t)(rb + mi * 16 + j) * ldc + cb + ni * 16] = (bf16)val;
      }
}

// ---- stage C: fused q||v projection (65536 x 256 each, K=512), r10 core ----
__global__ __launch_bounds__(256) void qv_kernel(
    const bf16* __restrict__ H, const float* __restrict__ Wq,
    const float* __restrict__ Wv, const float* __restrict__ bq,
    const float* __restrict__ bv, bf16* __restrict__ qvout) {
  __shared__ __align__(16) char lds[73728];
  const int bid = blockIdx.x;                     // 2048 blocks
  const int lid = (bid & 7) * 256 + (bid >> 3);
  const int x = lid & 3, y = lid >> 2;            // y: 0..511
  const float* Wsrc = (x < 2) ? Wq : Wv;
  f32x4_t acc[4][4];
#pragma unroll
  for (int i = 0; i < 4; ++i)
#pragma unroll
    for (int j = 0; j < 4; ++j) acc[i][j] = (f32x4_t){0.f, 0.f, 0.f, 0.f};
  core_deep3_0(H + (size_t)(y * 128) * 512, 512,
               Wsrc + (size_t)((x & 1) * 128) * 512, 512, 512, lds, acc);
  const float* bias = (x < 2) ? bq + x * 128 : bv + (x - 2) * 128;
  epi_bf16<0>(acc, qvout + (size_t)(y * 128) * 512 + x * 128, 512, bias);
}

// ---- stage E: W1 GEMM (K=1024, ldw=1028) + pred_scores rank-4 fixup ----
__global__ __launch_bounds__(256) void w1_kernel(
    const bf16* __restrict__ zb, const float* __restrict__ W1,
    const float* __restrict__ b1, const float* __restrict__ ps,
    float* __restrict__ obuf) {
  __shared__ __align__(16) char lds[73728];
  const int bid = blockIdx.x;                     // 256 blocks
  const int lid = (bid & 7) * 32 + (bid >> 3);
  const int x = lid & 1, y = lid >> 1;            // y: 0..127
  f32x4_t acc[4][4];
#pragma unroll
  for (int i = 0; i < 4; ++i)
#pragma unroll
    for (int j = 0; j < 4; ++j) acc[i][j] = (f32x4_t){0.f, 0.f, 0.f, 0.f};
  core_deep3_0(zb + (size_t)(y * 128) * 1024, 1024,
               W1 + (size_t)(x * 128) * 1028, 1028, 1024, lds, acc);

  const int lane = threadIdx.x & 63;
  const int wid  = threadIdx.x >> 6;
  const int wm = wid >> 1, wn = wid & 1;
  const int fr = lane & 15;
  const int rb = wm * 64 + 4 * (lane >> 4);
  const int cb = x * 128 + wn * 64 + fr;
  float bv[4], wt[4][4];
#pragma unroll
  for (int ni = 0; ni < 4; ++ni) {
    bv[ni] = b1[cb + ni * 16];
#pragma unroll
    for (int m = 0; m < 4; ++m) wt[ni][m] = W1[(size_t)(cb + ni * 16) * 1028 + 1024 + m];
  }
#pragma unroll
  for (int mi = 0; mi < 4; ++mi)
#pragma unroll
    for (int j = 0; j < 4; ++j) {
      const int r = y * 128 + rb + mi * 16 + j;
      f32x4_t psv = *(const f32x4_t*)(ps + (size_t)r * 4);
#pragma unroll
      for (int ni = 0; ni < 4; ++ni) {
        float val = acc[mi][ni][j] + bv[ni]
                  + psv[0] * wt[ni][0] + psv[1] * wt[ni][1]
                  + psv[2] * wt[ni][2] + psv[3] * wt[ni][3];
        obuf[(size_t)r * 256 + cb + ni * 16] = val;
      }
    }
}

// ---- prep: convert intra weights f32 -> bf16 ----
__device__ __forceinline__ void cp8(bf16* d, const float* s) {
  f32x4_t x0 = *(const f32x4_t*)s;
  f32x4_t x1 = *(const f32x4_t*)(s + 4);
  *(bf16x8_t*)d = cvt8(x0, x1);
}
__global__ __launch_bounds__(256) void prep_kernel(
    const float* __restrict__ w0, const float* __restrict__ w1s,
    const float* __restrict__ w2, const float* __restrict__ w3,
    bf16* __restrict__ o0, bf16* __restrict__ o1,
    bf16* __restrict__ o2, bf16* __restrict__ o3) {
  const int t = blockIdx.x * 256 + threadIdx.x;
  if (t < 65536)       { size_t i = (size_t)t * 8;            cp8(o0 + i, w0 + i); }
  else if (t < 114688) { size_t i = (size_t)(t - 65536) * 8;  cp8(o1 + i, w1s + i); }
  else if (t < 147456) { size_t i = (size_t)(t - 114688) * 8; cp8(o2 + i, w2 + i); }
  else                 { size_t i = (size_t)(t - 147456) * 8; cp8(o3 + i, w3 + i); }
}

// ---- attention: 4x4 scores (k=q per source bug), softmax(-UW*(vi+vj)), z=s@v ----
__global__ __launch_bounds__(256)
void attn_kernel(const bf16* __restrict__ qv, const float* __restrict__ pvars,
                 bf16* __restrict__ z) {
  const int b    = blockIdx.x * 4 + (threadIdx.x >> 6);
  const int lane = threadIdx.x & 63;
  float qf[4][4], vf[4][4];
#pragma unroll
  for (int i = 0; i < 4; ++i) {
    const bf16* row = qv + ((size_t)b * 4 + i) * 512;
    bf16x4_t qq = *(const bf16x4_t*)(row + lane * 4);
    bf16x4_t vv = *(const bf16x4_t*)(row + 256 + lane * 4);
#pragma unroll
    for (int c = 0; c < 4; ++c) { qf[i][c] = (float)qq[c]; vf[i][c] = (float)vv[c]; }
  }
  float s[4][4];
#pragma unroll
  for (int i = 0; i < 4; ++i)
#pragma unroll
    for (int j = 0; j < 4; ++j)
      s[i][j] = qf[i][0] * qf[j][0] + qf[i][1] * qf[j][1] + qf[i][2] * qf[j][2] + qf[i][3] * qf[j][3];
#pragma unroll
  for (int off = 1; off < 64; off <<= 1)
#pragma unroll
    for (int i = 0; i < 4; ++i)
#pragma unroll
      for (int j = 0; j < 4; ++j) s[i][j] += __shfl_xor(s[i][j], off);

  float var4[4];
#pragma unroll
  for (int m = 0; m < 4; ++m) var4[m] = pvars[(size_t)b * 4 + m];
  float w[4][4];
#pragma unroll
  for (int i = 0; i < 4; ++i) {
    float t[4]; float mx = -1e30f;
#pragma unroll
    for (int j = 0; j < 4; ++j) { t[j] = s[i][j] - 0.1f * (var4[i] + var4[j]); mx = fmaxf(mx, t[j]); }
    float sum = 0.f;
#pragma unroll
    for (int j = 0; j < 4; ++j) { t[j] = expf(t[j] - mx); sum += t[j]; }
    const float is = 1.f / sum;
#pragma unroll
    for (int j = 0; j < 4; ++j) w[i][j] = t[j] * is;
  }
#pragma unroll
  for (int i = 0; i < 4; ++i) {
    bf16x4_t zo;
#pragma unroll
    for (int c = 0; c < 4; ++c) {
      float zf = w[i][0] * vf[0][c] + w[i][1] * vf[1][c] + w[i][2] * vf[2][c] + w[i][3] * vf[3][c];
      zo[c] = (bf16)zf;
    }
    *(bf16x4_t*)(z + ((size_t)b * 4 + i) * 256 + lane * 4) = zo;
  }
}

// ---- final fc (256 -> 1) + sigmoid ----
__global__ __launch_bounds__(256)
void fc_kernel(const float* __restrict__ o, const float* __restrict__ wfc,
               const float* __restrict__ bfc, float* __restrict__ out) {
  const int b    = blockIdx.x * 4 + (threadIdx.x >> 6);
  const int lane = threadIdx.x & 63;
  f32x4_t ov = *(const f32x4_t*)(o + (size_t)b * 256 + lane * 4);
  f32x4_t wv = *(const f32x4_t*)(wfc + lane * 4);
  float p = ov[0] * wv[0] + ov[1] * wv[1] + ov[2] * wv[2] + ov[3] * wv[3];
#pragma unroll
  for (int off = 1; off < 64; off <<= 1) p += __shfl_xor(p, off);
  if (lane == 0) {
    const float lg = p + bfc[0];
    out[b] = 1.f / (1.f + expf(-lg));
  }
}

extern "C" void kernel_launch(void* const* d_in, const int* in_sizes, int n_in,
                              void* d_out, int out_size, void* d_ws, size_t ws_size,
                              hipStream_t stream) {
  (void)in_sizes; (void)n_in; (void)out_size; (void)ws_size;
  const float* feat[4] = {(const float*)d_in[0], (const float*)d_in[3],
                          (const float*)d_in[6], (const float*)d_in[9]};
  const float* Wi[4]   = {(const float*)d_in[1], (const float*)d_in[4],
                          (const float*)d_in[7], (const float*)d_in[10]};
  const float* bi[4]   = {(const float*)d_in[2], (const float*)d_in[5],
                          (const float*)d_in[8], (const float*)d_in[11]};
  const float* ps  = (const float*)d_in[12];
  const float* pv  = (const float*)d_in[13];
  const float* lng = (const float*)d_in[14];
  const float* lnb = (const float*)d_in[15];
  const float* Wq  = (const float*)d_in[16];
  const float* bq  = (const float*)d_in[17];
  const float* Wv  = (const float*)d_in[20];
  const float* bvp = (const float*)d_in[21];
  const float* W1  = (const float*)d_in[22];
  const float* b1  = (const float*)d_in[23];
  const float* Wfc = (const float*)d_in[24];
  const float* bfc = (const float*)d_in[25];

  char* ws = (char*)d_ws;
  const size_t MB = 1024 * 1024;
  bf16*  hbuf  = (bf16*)ws;                        // [0,64M): H (intra_ln out)
  bf16*  zbuf  = (bf16*)ws;                        // [0,32M): z (after stage C)
  float* obuf  = (float*)(ws + 32 * MB);           // [32M,48M)
  bf16*  wb0   = (bf16*)(ws + 64 * MB);            // intra only
  bf16*  wb1   = (bf16*)(ws + 65 * MB);
  bf16*  wb2   = (bf16*)(ws + 65 * MB + 786432);
  bf16*  wb3   = (bf16*)(ws + 66 * MB + 262144);
  bf16*  qvout = (bf16*)(ws + 64 * MB);            // stage C (clobbers wb*)

  hipLaunchKernelGGL(prep_kernel, dim3(736), dim3(256), 0, stream,
                     Wi[0], Wi[1], Wi[2], Wi[3], wb0, wb1, wb2, wb3);
  hipLaunchKernelGGL(intra_ln_kernel, dim3(512), dim3(512), 0, stream,
                     feat[0], feat[1], feat[2], feat[3],
                     wb0, wb1, wb2, wb3, bi[0], bi[1], bi[2], bi[3],
                     lng, lnb, hbuf);
  hipLaunchKernelGGL(qv_kernel, dim3(2048), dim3(256), 0, stream,
                     hbuf, Wq, Wv, bq, bvp, qvout);
  hipLaunchKernelGGL(attn_kernel, dim3(16384 / 4), dim3(256), 0, stream, qvout, pv, zbuf);
  hipLaunchKernelGGL(w1_kernel, dim3(256), dim3(256), 0, stream, zbuf, W1, b1, ps, obuf);
  hipLaunchKernelGGL(fc_kernel, dim3(16384 / 4), dim3(256), 0, stream, obuf, Wfc, bfc, (float*)d_out);
}

// Round 14
// 228.730 us; speedup vs baseline: 1.2612x; 1.0402x over previous
//
#include <hip/hip_runtime.h>
#include <hip/hip_bf16.h>

// ---------------------------------------------------------------------------
// HybridFusionNetworkWithUncertainty — MI355X (gfx950), round 14
// r13 failed to COMPILE: initialized array of LDS pointers -> addrspacecast
// static initializer (unsupported). Fix: integer byte offsets computed
// per-use (lds + bcur*32768 etc). Pipeline logic identical to r13's intent:
//   B bf16 [512][32] x3 bufs (96K) via gl_lds, staged 2 phases ahead;
//   A f32 reg-staged (2 dwordx4, 1 phase ahead) -> bf16 commit, 2x8K bufs;
//   total 112KB; wait vmcnt(4) retires {B(t),Ald(t)}, B(t+1) stays in
//   flight across barriers. FIFO per iter: Ald(t+1) then B(t+2).
// qv/w1/attn/fc/prep + LN epilogue + mapping = r12 verbatim (passing).
// ws: H [0,64M); zbuf [0,32M); obuf [32M,48M); wb0-3 @64M (intra only);
//     qvout [64M,128M) (stage C clobbers wb*).
// ---------------------------------------------------------------------------

typedef __bf16 bf16;
typedef __bf16 bf16x4_t __attribute__((ext_vector_type(4)));
typedef __bf16 bf16x8_t __attribute__((ext_vector_type(8)));
typedef float  f32x4_t  __attribute__((ext_vector_type(4)));

__device__ __forceinline__ bf16x8_t cvt8(f32x4_t a, f32x4_t b) {
  bf16x8_t r;
  r[0] = (bf16)a[0]; r[1] = (bf16)a[1]; r[2] = (bf16)a[2]; r[3] = (bf16)a[3];
  r[4] = (bf16)b[0]; r[5] = (bf16)b[1]; r[6] = (bf16)b[2]; r[7] = (bf16)b[3];
  return r;
}

__device__ __forceinline__ void gl_lds16(const void* g, void* l) {
  __builtin_amdgcn_global_load_lds(
      (const __attribute__((address_space(1))) void*)g,
      (__attribute__((address_space(3))) void*)l, 16, 0, 0);
}

#define SBAR()   __builtin_amdgcn_s_barrier()
#define SCHED0() __builtin_amdgcn_sched_barrier(0)

// bf16 tile rows of 32 bf16 (64B): chunk c of row r at c^((r>>1)&3)
__device__ __forceinline__ bf16x8_t frag_b16(const bf16* Ts, int row, int c0) {
  const int byte = row * 64 + ((c0 ^ ((row >> 1) & 3)) << 4);
  return *(const bf16x8_t*)((const char*)Ts + byte);
}
// f32 tile rows of 32 f32 (128B): 16B chunk q of row r at q^(r&7)
__device__ __forceinline__ bf16x8_t frag_f32(const float* Ts, int row, int g) {
  const int p0 = (2 * g)     ^ (row & 7);
  const int p1 = (2 * g + 1) ^ (row & 7);
  f32x4_t lo = *(const f32x4_t*)((const char*)Ts + row * 128 + (p0 << 4));
  f32x4_t hi = *(const f32x4_t*)((const char*)Ts + row * 128 + (p1 << 4));
  return cvt8(lo, hi);
}

// ---- 512-thread staging: bf16 [512][32] (32KB), 4 gl_lds/thread ----
__device__ __forceinline__ void stage_b512x32(const bf16* __restrict__ src, int ld,
                                              int k0, bf16* lds) {
  const int l = threadIdx.x & 63;
  const int w = threadIdx.x >> 6;
#pragma unroll
  for (int j = 0; j < 4; ++j) {
    const int rb = w * 64 + j * 16;
    const int r  = rb + (l >> 2);
    const int sc = (l & 3) ^ ((r >> 1) & 3);
    gl_lds16(src + (size_t)r * ld + k0 + sc * 8, (char*)lds + rb * 64);
  }
}

// ---- stage A (fused): intra GEMM 128x512 + relu + LN -> H ----
__global__ __launch_bounds__(512) void intra_ln_kernel(
    const float* __restrict__ f0, const float* __restrict__ f1,
    const float* __restrict__ f2, const float* __restrict__ f3,
    const bf16* __restrict__ wb0, const bf16* __restrict__ wb1,
    const bf16* __restrict__ wb2, const bf16* __restrict__ wb3,
    const float* __restrict__ bb0, const float* __restrict__ bb1,
    const float* __restrict__ bb2, const float* __restrict__ bb3,
    const float* __restrict__ lng, const float* __restrict__ lnb,
    bf16* __restrict__ Hout) {
  __shared__ __align__(16) char lds[114688];       // B 3x32K + A 2x8K = 112KB

  const int bid  = blockIdx.x;                     // 512 blocks
  const int p    = bid & 255, half = bid >> 8;
  const int px   = (p & 7) * 32 + (p >> 3);        // XCD-chunked bijection
  int z = px & 3, y = px >> 2;                     // y 0..63
  if (half) { z ^= 2; y += 64; }                   // complementary K pairing
  const float* fp; const bf16* wp; const float* bp; int K;
  switch (z) {
    case 0:  fp = f0; wp = wb0; bp = bb0; K = 1024; break;
    case 1:  fp = f1; wp = wb1; bp = bb1; K = 768;  break;
    case 2:  fp = f2; wp = wb2; bp = bb2; K = 512;  break;
    default: fp = f3; wp = wb3; bp = bb3; K = 640;  break;
  }
  const float* A = fp + (size_t)(y * 128) * K;
  const bf16*  B = wp;
  const int tid = threadIdx.x;
  const int lane = tid & 63;
  const int wid  = tid >> 6;                       // 0..7
  const int wm = wid >> 2, wn = wid & 3;           // wave = 64 rows x 128 cols
  const int fr = lane & 15, g = lane >> 4;

  // A staging geometry: 4 thr/row, 8 f32 each -> one 16B bf16 chunk
  const int srow = tid >> 2, sq = tid & 3;
  const float* Af = A + (size_t)srow * K + sq * 8;
  const int abyte = srow * 64 + ((sq ^ ((srow >> 1) & 3)) << 4);

  f32x4_t acc[4][8];
#pragma unroll
  for (int i = 0; i < 4; ++i)
#pragma unroll
    for (int j = 0; j < 8; ++j) acc[i][j] = (f32x4_t){0.f, 0.f, 0.f, 0.f};

  const int nt = K >> 5;                           // 16..32, always even

  // prologue FIFO: B(0)[4], Ald(0)[2], B(1)[4]
  stage_b512x32(B, K, 0, (bf16*)(lds));
  f32x4_t aA0 = *(const f32x4_t*)(Af + 0);
  f32x4_t aA1 = *(const f32x4_t*)(Af + 4);
  stage_b512x32(B, K, 32, (bf16*)(lds + 32768));
  f32x4_t aB0, aB1;

  int bcur = 0;                                    // B buffer index for tile t
#define INTRA_ITER(T, C0, C1, N0, N1)                                         \
  {                                                                           \
    const int t_ = (T);                                                       \
    if (t_ < nt - 1) asm volatile("s_waitcnt vmcnt(4)" ::: "memory");         \
    else             asm volatile("s_waitcnt vmcnt(0)" ::: "memory");         \
    *(bf16x8_t*)(lds + 98304 + (t_ & 1) * 8192 + abyte) = cvt8(C0, C1);       \
    asm volatile("s_waitcnt lgkmcnt(0)" ::: "memory");                        \
    SBAR(); SCHED0();                                                         \
    if (t_ + 1 < nt) {                                                        \
      N0 = *(const f32x4_t*)(Af + (t_ + 1) * 32);                             \
      N1 = *(const f32x4_t*)(Af + (t_ + 1) * 32 + 4);                         \
    }                                                                         \
    SCHED0();                                                                 \
    __builtin_amdgcn_s_setprio(1);                                            \
    {                                                                         \
      const bf16* Ac = (const bf16*)(lds + 98304 + (t_ & 1) * 8192);          \
      const bf16* Bc = (const bf16*)(lds + bcur * 32768);                     \
      bf16x8_t ar[4], br[8];                                                  \
      _Pragma("unroll")                                                       \
      for (int mi = 0; mi < 4; ++mi) ar[mi] = frag_b16(Ac, wm * 64 + mi * 16 + fr, g); \
      _Pragma("unroll")                                                       \
      for (int ni = 0; ni < 8; ++ni) br[ni] = frag_b16(Bc, wn * 128 + ni * 16 + fr, g); \
      _Pragma("unroll")                                                       \
      for (int mi = 0; mi < 4; ++mi)                                          \
        _Pragma("unroll")                                                     \
        for (int ni = 0; ni < 8; ++ni)                                        \
          acc[mi][ni] = __builtin_amdgcn_mfma_f32_16x16x32_bf16(ar[mi], br[ni], acc[mi][ni], 0, 0, 0); \
    }                                                                         \
    __builtin_amdgcn_s_setprio(0);                                            \
    SCHED0(); SBAR();                                                         \
    const int bn_ = (bcur == 2) ? 0 : bcur + 1;    /* buf of tile t+1 */      \
    const int b2_ = (bn_ == 2) ? 0 : bn_ + 1;      /* buf for tile t+2 */     \
    if (t_ + 2 < nt) stage_b512x32(B, K, (t_ + 2) * 32, (bf16*)(lds + b2_ * 32768)); \
    bcur = bn_;                                                               \
  }

  for (int t = 0; t < nt; t += 2) {
    INTRA_ITER(t,     aA0, aA1, aB0, aB1)
    INTRA_ITER(t + 1, aB0, aB1, aA0, aA1)
  }
#undef INTRA_ITER

  // ---- fused LayerNorm epilogue (r12-proven) ----
  float* part  = (float*)lds;                      // [8][64][2] = 4KB
  float* muinv = (float*)(lds + 4096);             // [128][2]   = 1KB
  float bv8[8];
#pragma unroll
  for (int ni = 0; ni < 8; ++ni) bv8[ni] = bp[wn * 128 + ni * 16 + fr];
#pragma unroll
  for (int mi = 0; mi < 4; ++mi)
#pragma unroll
    for (int j = 0; j < 4; ++j) {
      float s = 0.f, s2 = 0.f;
#pragma unroll
      for (int ni = 0; ni < 8; ++ni) {
        float v = fmaxf(acc[mi][ni][j] + bv8[ni], 0.f);
        s += v; s2 += v * v;
      }
#pragma unroll
      for (int off = 1; off < 16; off <<= 1) {
        s += __shfl_xor(s, off); s2 += __shfl_xor(s2, off);
      }
      if (fr == 0) {
        const int rl = mi * 16 + 4 * g + j;        // 0..63
        part[(wid * 64 + rl) * 2]     = s;
        part[(wid * 64 + rl) * 2 + 1] = s2;
      }
    }
  __syncthreads();
  if (tid < 128) {
    const int wmt = tid >> 6, rl = tid & 63;
    float s = 0.f, s2 = 0.f;
#pragma unroll
    for (int q = 0; q < 4; ++q) {
      s  += part[((wmt * 4 + q) * 64 + rl) * 2];
      s2 += part[((wmt * 4 + q) * 64 + rl) * 2 + 1];
    }
    const float mu  = s * (1.f / 512.f);
    const float var = s2 * (1.f / 512.f) - mu * mu;
    muinv[tid * 2]     = mu;
    muinv[tid * 2 + 1] = rsqrtf(var + 1e-5f);
  }
  __syncthreads();
  float gg[8], be[8];
#pragma unroll
  for (int ni = 0; ni < 8; ++ni) {
    const int col = wn * 128 + ni * 16 + fr;
    gg[ni] = lng[col]; be[ni] = lnb[col];
  }
#pragma unroll
  for (int mi = 0; mi < 4; ++mi)
#pragma unroll
    for (int j = 0; j < 4; ++j) {
      const int row = wm * 64 + mi * 16 + 4 * g + j;
      const float mu  = muinv[row * 2];
      const float inv = muinv[row * 2 + 1];
      bf16* hp = Hout + (size_t)(y * 128 + row) * 2048 + z * 512;
#pragma unroll
      for (int ni = 0; ni < 8; ++ni) {
        float v = fmaxf(acc[mi][ni][j] + bv8[ni], 0.f);
        hp[wn * 128 + ni * 16 + fr] = (bf16)((v - mu) * inv * gg[ni] + be[ni]);
      }
    }
}

// ================= 256-thread helpers (qv/w1, r12-verified) =================
__device__ __forceinline__ void stage_b16(const bf16* __restrict__ src, int ld,
                                          int k0, bf16* lds) {
  const int l = threadIdx.x & 63;
  const int w = threadIdx.x >> 6;
#pragma unroll
  for (int j = 0; j < 2; ++j) {
    const int rb = w * 32 + j * 16;
    const int r  = rb + (l >> 2);
    const int sc = (l & 3) ^ ((r >> 1) & 3);
    gl_lds16(src + (size_t)r * ld + k0 + sc * 8, (char*)lds + rb * 64);
  }
}
__device__ __forceinline__ void stage_f32(const float* __restrict__ src, int ld,
                                          int k0, float* lds) {
  const int l = threadIdx.x & 63;
  const int w = threadIdx.x >> 6;
#pragma unroll
  for (int j = 0; j < 4; ++j) {
    const int rb = w * 32 + j * 8;
    const int r  = rb + (l >> 3);
    const int q  = (l & 7) ^ (r & 7);
    gl_lds16(src + (size_t)r * ld + k0 + q * 4, (char*)lds + rb * 128);
  }
}
__device__ __forceinline__ void mfma_deep0(const char* buf, f32x4_t acc[4][4]) {
  const int lane = threadIdx.x & 63;
  const int wid  = threadIdx.x >> 6;
  const int wm = wid >> 1, wn = wid & 1;
  const int fr = lane & 15, g = lane >> 4;
  const bf16*  Ab = (const bf16*)buf;
  const float* Bf = (const float*)(buf + 8192);
  bf16x8_t ar[4], br[4];
#pragma unroll
  for (int mi = 0; mi < 4; ++mi) ar[mi] = frag_b16(Ab, wm * 64 + mi * 16 + fr, g);
#pragma unroll
  for (int ni = 0; ni < 4; ++ni) br[ni] = frag_f32(Bf, wn * 64 + ni * 16 + fr, g);
#pragma unroll
  for (int mi = 0; mi < 4; ++mi)
#pragma unroll
    for (int ni = 0; ni < 4; ++ni)
      acc[mi][ni] = __builtin_amdgcn_mfma_f32_16x16x32_bf16(ar[mi], br[ni], acc[mi][ni], 0, 0, 0);
}
__device__ __forceinline__ void core_deep3_0(const void* A, int lda, const void* B,
                                             int ldb, int K, char* lds,
                                             f32x4_t acc[4][4]) {
  const int nt = K >> 5;
  auto stage = [&](int t, char* buf) {
    stage_b16((const bf16*)A, lda, t * 32, (bf16*)buf);
    stage_f32((const float*)B, ldb, t * 32, (float*)(buf + 8192));
  };
  stage(0, lds); stage(1, lds + 24576); stage(2, lds + 49152);
  int bsel = 0;
  for (int t = 0; t < nt; ++t) {
    const int ahead = nt - 1 - t;
    if (ahead >= 2)      asm volatile("s_waitcnt vmcnt(12)" ::: "memory");
    else if (ahead == 1) asm volatile("s_waitcnt vmcnt(6)"  ::: "memory");
    else                 asm volatile("s_waitcnt vmcnt(0)"  ::: "memory");
    SBAR(); SCHED0();
    __builtin_amdgcn_s_setprio(1);
    mfma_deep0(lds + bsel * 24576, acc);
    __builtin_amdgcn_s_setprio(0);
    SCHED0(); SBAR();
    if (t + 3 < nt) stage(t + 3, lds + bsel * 24576);
    bsel = (bsel == 2) ? 0 : bsel + 1;
  }
}
template<int RELU>
__device__ __forceinline__ void epi_bf16(f32x4_t acc[4][4], bf16* __restrict__ C, int ldc,
                                         const float* __restrict__ bias) {
  const int lane = threadIdx.x & 63;
  const int wid  = threadIdx.x >> 6;
  const int wm = wid >> 1, wn = wid & 1;
  const int fr = lane & 15;
  const int rb = wm * 64 + 4 * (lane >> 4);
  const int cb = wn * 64 + fr;
  float bv[4];
#pragma unroll
  for (int ni = 0; ni < 4; ++ni) bv[ni] = bias[cb + ni * 16];
#pragma unroll
  for (int mi = 0; mi < 4; ++mi)
#pragma unroll
    for (int j = 0; j < 4; ++j)
#pragma unroll
      for (int ni = 0; ni < 4; ++ni) {
        float val = acc[mi][ni][j] + bv[ni];
        if (RELU) val = fmaxf(val, 0.f);
        C[(size_t)(rb + mi * 16 + j) * ldc + cb + ni * 16] = (bf16)val;
      }
}

// ---- stage C: fused q||v projection (65536 x 256 each, K=512) ----
__global__ __launch_bounds__(256) void qv_kernel(
    const bf16* __restrict__ H, const float* __restrict__ Wq,
    const float* __restrict__ Wv, const float* __restrict__ bq,
    const float* __restrict__ bv, bf16* __restrict__ qvout) {
  __shared__ __align__(16) char lds[73728];
  const int bid = blockIdx.x;                     // 2048 blocks
  const int lid = (bid & 7) * 256 + (bid >> 3);
  const int x = lid & 3, y = lid >> 2;            // y: 0..511
  const float* Wsrc = (x < 2) ? Wq : Wv;
  f32x4_t acc[4][4];
#pragma unroll
  for (int i = 0; i < 4; ++i)
#pragma unroll
    for (int j = 0; j < 4; ++j) acc[i][j] = (f32x4_t){0.f, 0.f, 0.f, 0.f};
  core_deep3_0(H + (size_t)(y * 128) * 512, 512,
               Wsrc + (size_t)((x & 1) * 128) * 512, 512, 512, lds, acc);
  const float* bias = (x < 2) ? bq + x * 128 : bv + (x - 2) * 128;
  epi_bf16<0>(acc, qvout + (size_t)(y * 128) * 512 + x * 128, 512, bias);
}

// ---- stage E: W1 GEMM (K=1024, ldw=1028) + pred_scores rank-4 fixup ----
__global__ __launch_bounds__(256) void w1_kernel(
    const bf16* __restrict__ zb, const float* __restrict__ W1,
    const float* __restrict__ b1, const float* __restrict__ ps,
    float* __restrict__ obuf) {
  __shared__ __align__(16) char lds[73728];
  const int bid = blockIdx.x;                     // 256 blocks
  const int lid = (bid & 7) * 32 + (bid >> 3);
  const int x = lid & 1, y = lid >> 1;            // y: 0..127
  f32x4_t acc[4][4];
#pragma unroll
  for (int i = 0; i < 4; ++i)
#pragma unroll
    for (int j = 0; j < 4; ++j) acc[i][j] = (f32x4_t){0.f, 0.f, 0.f, 0.f};
  core_deep3_0(zb + (size_t)(y * 128) * 1024, 1024,
               W1 + (size_t)(x * 128) * 1028, 1028, 1024, lds, acc);

  const int lane = threadIdx.x & 63;
  const int wid  = threadIdx.x >> 6;
  const int wm = wid >> 1, wn = wid & 1;
  const int fr = lane & 15;
  const int rb = wm * 64 + 4 * (lane >> 4);
  const int cb = x * 128 + wn * 64 + fr;
  float bv[4], wt[4][4];
#pragma unroll
  for (int ni = 0; ni < 4; ++ni) {
    bv[ni] = b1[cb + ni * 16];
#pragma unroll
    for (int m = 0; m < 4; ++m) wt[ni][m] = W1[(size_t)(cb + ni * 16) * 1028 + 1024 + m];
  }
#pragma unroll
  for (int mi = 0; mi < 4; ++mi)
#pragma unroll
    for (int j = 0; j < 4; ++j) {
      const int r = y * 128 + rb + mi * 16 + j;
      f32x4_t psv = *(const f32x4_t*)(ps + (size_t)r * 4);
#pragma unroll
      for (int ni = 0; ni < 4; ++ni) {
        float val = acc[mi][ni][j] + bv[ni]
                  + psv[0] * wt[ni][0] + psv[1] * wt[ni][1]
                  + psv[2] * wt[ni][2] + psv[3] * wt[ni][3];
        obuf[(size_t)r * 256 + cb + ni * 16] = val;
      }
    }
}

// ---- prep: convert intra weights f32 -> bf16 ----
__device__ __forceinline__ void cp8(bf16* d, const float* s) {
  f32x4_t x0 = *(const f32x4_t*)s;
  f32x4_t x1 = *(const f32x4_t*)(s + 4);
  *(bf16x8_t*)d = cvt8(x0, x1);
}
__global__ __launch_bounds__(256) void prep_kernel(
    const float* __restrict__ w0, const float* __restrict__ w1s,
    const float* __restrict__ w2, const float* __restrict__ w3,
    bf16* __restrict__ o0, bf16* __restrict__ o1,
    bf16* __restrict__ o2, bf16* __restrict__ o3) {
  const int t = blockIdx.x * 256 + threadIdx.x;
  if (t < 65536)       { size_t i = (size_t)t * 8;            cp8(o0 + i, w0 + i); }
  else if (t < 114688) { size_t i = (size_t)(t - 65536) * 8;  cp8(o1 + i, w1s + i); }
  else if (t < 147456) { size_t i = (size_t)(t - 114688) * 8; cp8(o2 + i, w2 + i); }
  else                 { size_t i = (size_t)(t - 147456) * 8; cp8(o3 + i, w3 + i); }
}

// ---- attention: 4x4 scores (k=q per source bug), softmax(-UW*(vi+vj)), z=s@v ----
__global__ __launch_bounds__(256)
void attn_kernel(const bf16* __restrict__ qv, const float* __restrict__ pvars,
                 bf16* __restrict__ z) {
  const int b    = blockIdx.x * 4 + (threadIdx.x >> 6);
  const int lane = threadIdx.x & 63;
  float qf[4][4], vf[4][4];
#pragma unroll
  for (int i = 0; i < 4; ++i) {
    const bf16* row = qv + ((size_t)b * 4 + i) * 512;
    bf16x4_t qq = *(const bf16x4_t*)(row + lane * 4);
    bf16x4_t vv = *(const bf16x4_t*)(row + 256 + lane * 4);
#pragma unroll
    for (int c = 0; c < 4; ++c) { qf[i][c] = (float)qq[c]; vf[i][c] = (float)vv[c]; }
  }
  float s[4][4];
#pragma unroll
  for (int i = 0; i < 4; ++i)
#pragma unroll
    for (int j = 0; j < 4; ++j)
      s[i][j] = qf[i][0] * qf[j][0] + qf[i][1] * qf[j][1] + qf[i][2] * qf[j][2] + qf[i][3] * qf[j][3];
#pragma unroll
  for (int off = 1; off < 64; off <<= 1)
#pragma unroll
    for (int i = 0; i < 4; ++i)
#pragma unroll
      for (int j = 0; j < 4; ++j) s[i][j] += __shfl_xor(s[i][j], off);

  float var4[4];
#pragma unroll
  for (int m = 0; m < 4; ++m) var4[m] = pvars[(size_t)b * 4 + m];
  float w[4][4];
#pragma unroll
  for (int i = 0; i < 4; ++i) {
    float t[4]; float mx = -1e30f;
#pragma unroll
    for (int j = 0; j < 4; ++j) { t[j] = s[i][j] - 0.1f * (var4[i] + var4[j]); mx = fmaxf(mx, t[j]); }
    float sum = 0.f;
#pragma unroll
    for (int j = 0; j < 4; ++j) { t[j] = expf(t[j] - mx); sum += t[j]; }
    const float is = 1.f / sum;
#pragma unroll
    for (int j = 0; j < 4; ++j) w[i][j] = t[j] * is;
  }
#pragma unroll
  for (int i = 0; i < 4; ++i) {
    bf16x4_t zo;
#pragma unroll
    for (int c = 0; c < 4; ++c) {
      float zf = w[i][0] * vf[0][c] + w[i][1] * vf[1][c] + w[i][2] * vf[2][c] + w[i][3] * vf[3][c];
      zo[c] = (bf16)zf;
    }
    *(bf16x4_t*)(z + ((size_t)b * 4 + i) * 256 + lane * 4) = zo;
  }
}

// ---- final fc (256 -> 1) + sigmoid ----
__global__ __launch_bounds__(256)
void fc_kernel(const float* __restrict__ o, const float* __restrict__ wfc,
               const float* __restrict__ bfc, float* __restrict__ out) {
  const int b    = blockIdx.x * 4 + (threadIdx.x >> 6);
  const int lane = threadIdx.x & 63;
  f32x4_t ov = *(const f32x4_t*)(o + (size_t)b * 256 + lane * 4);
  f32x4_t wv = *(const f32x4_t*)(wfc + lane * 4);
  float p = ov[0] * wv[0] + ov[1] * wv[1] + ov[2] * wv[2] + ov[3] * wv[3];
#pragma unroll
  for (int off = 1; off < 64; off <<= 1) p += __shfl_xor(p, off);
  if (lane == 0) {
    const float lg = p + bfc[0];
    out[b] = 1.f / (1.f + expf(-lg));
  }
}

extern "C" void kernel_launch(void* const* d_in, const int* in_sizes, int n_in,
                              void* d_out, int out_size, void* d_ws, size_t ws_size,
                              hipStream_t stream) {
  (void)in_sizes; (void)n_in; (void)out_size; (void)ws_size;
  const float* feat[4] = {(const float*)d_in[0], (const float*)d_in[3],
                          (const float*)d_in[6], (const float*)d_in[9]};
  const float* Wi[4]   = {(const float*)d_in[1], (const float*)d_in[4],
                          (const float*)d_in[7], (const float*)d_in[10]};
  const float* bi[4]   = {(const float*)d_in[2], (const float*)d_in[5],
                          (const float*)d_in[8], (const float*)d_in[11]};
  const float* ps  = (const float*)d_in[12];
  const float* pv  = (const float*)d_in[13];
  const float* lng = (const float*)d_in[14];
  const float* lnb = (const float*)d_in[15];
  const float* Wq  = (const float*)d_in[16];
  const float* bq  = (const float*)d_in[17];
  const float* Wv  = (const float*)d_in[20];
  const float* bvp = (const float*)d_in[21];
  const float* W1  = (const float*)d_in[22];
  const float* b1  = (const float*)d_in[23];
  const float* Wfc = (const float*)d_in[24];
  const float* bfc = (const float*)d_in[25];

  char* ws = (char*)d_ws;
  const size_t MB = 1024 * 1024;
  bf16*  hbuf  = (bf16*)ws;                        // [0,64M): H (intra_ln out)
  bf16*  zbuf  = (bf16*)ws;                        // [0,32M): z (after stage C)
  float* obuf  = (float*)(ws + 32 * MB);           // [32M,48M)
  bf16*  wb0   = (bf16*)(ws + 64 * MB);            // intra only
  bf16*  wb1   = (bf16*)(ws + 65 * MB);
  bf16*  wb2   = (bf16*)(ws + 65 * MB + 786432);
  bf16*  wb3   = (bf16*)(ws + 66 * MB + 262144);
  bf16*  qvout = (bf16*)(ws + 64 * MB);            // stage C (clobbers wb*)

  hipLaunchKernelGGL(prep_kernel, dim3(736), dim3(256), 0, stream,
                     Wi[0], Wi[1], Wi[2], Wi[3], wb0, wb1, wb2, wb3);
  hipLaunchKernelGGL(intra_ln_kernel, dim3(512), dim3(512), 0, stream,
                     feat[0], feat[1], feat[2], feat[3],
                     wb0, wb1, wb2, wb3, bi[0], bi[1], bi[2], bi[3],
                     lng, lnb, hbuf);
  hipLaunchKernelGGL(qv_kernel, dim3(2048), dim3(256), 0, stream,
                     hbuf, Wq, Wv, bq, bvp, qvout);
  hipLaunchKernelGGL(attn_kernel, dim3(16384 / 4), dim3(256), 0, stream, qvout, pv, zbuf);
  hipLaunchKernelGGL(w1_kernel, dim3(256), dim3(256), 0, stream, zbuf, W1, b1, ps, obuf);
  hipLaunchKernelGGL(fc_kernel, dim3(16384 / 4), dim3(256), 0, stream, obuf, Wfc, bfc, (float*)d_out);
}